// Round 4
// baseline (4849.697 us; speedup 1.0000x reference)
//
#include <hip/hip_runtime.h>
#include <hip/hip_bf16.h>
#include <stdint.h>

typedef __hip_bfloat16 bf16;
typedef __attribute__((ext_vector_type(8))) short frag16;
typedef __attribute__((ext_vector_type(4))) float f32x4;

#define B_ 2048
#define T_ 64
#define E_ 300
#define H_ 300
#define C_ 1024
#define NE_ 65536
#define HP 320     // padded E/H half of concat-K
#define KC 640     // padded concat K (320 x + 320 h)
#define NP 1280    // padded 4H, gate-interleaved n = 4*j + q
#define PADK 40    // LDS shorts per 32-k row (80B stride -> 2-way banks, free)

static __device__ __forceinline__ float sigf(float x) {
  x = fminf(fmaxf(x, -30.f), 30.f);
  return 1.f / (1.f + __expf(-x));
}
static __device__ __forceinline__ float tanhfast(float x) {
  x = fminf(fmaxf(x, -15.f), 15.f);
  float e = __expf(2.f * x);
  return (e - 1.f) / (e + 1.f);
}
static __device__ __forceinline__ float ldraw(const void* p, size_t i, int isb) {
  return isb ? __bfloat162float(((const bf16*)p)[i]) : ((const float*)p)[i];
}
static __device__ __forceinline__ short b2s(bf16 b) {
  short s; __builtin_memcpy(&s, &b, 2); return s;
}
static __device__ __forceinline__ short4 f4tob4(float4 v) {
  return make_short4(b2s(__float2bfloat16(v.x)), b2s(__float2bfloat16(v.y)),
                     b2s(__float2bfloat16(v.z)), b2s(__float2bfloat16(v.w)));
}

// Input dtype detector: bit14 of low half-word is 0 in bf16 world (|v|<2),
// ~Bernoulli(0.5) in f32 world (mantissa bits).
__global__ void detect_dtype(const unsigned short* __restrict__ e2, int* __restrict__ flag) {
  __shared__ int red[4];
  int tid = threadIdx.x;
  int ones = 0;
#pragma unroll
  for (int s = 0; s < 16; ++s) ones += (e2[2 * (tid * 16 + s)] >> 14) & 1;
  for (int off = 32; off > 0; off >>= 1) ones += __shfl_down(ones, off, 64);
  if ((tid & 63) == 0) red[tid >> 6] = ones;
  __syncthreads();
  if (tid == 0) {
    int tot = red[0] + red[1] + red[2] + red[3];
    *flag = (tot < 1024) ? 1 : 0;  // 1 = bf16 inputs, 0 = f32 inputs
  }
}

// C[m][n] = sum_k A[m][k]*W[n][k] (+bias[n]); M,N mult of 128, K of 32 (K/32 even).
// A/W always bf16 (raw phase-2 weights pre-converted), bias f32.
// LDS-staged A and B, padded rows (PADK), dist-2 paired register prefetch.
// If gridDim.z==2, blockIdx.z==1 uses the (A2,W2,bias2,Cf2) operand set
// (used to batch the two independent GRU gate GEMMs into one dispatch).
// outmode=1: d_out in raw dtype per *rawp (Cf/Cb alias d_out).
__global__ __launch_bounds__(256) void gemm_bt(
    const bf16* A, int lda, const bf16* W, int ldw, const float* bias,
    float* Cf, bf16* Cb, int ldc, int K,
    const int* __restrict__ rawp, int outmode,
    const bf16* A2, const bf16* W2, const float* bias2, float* Cf2) {
  if (blockIdx.z) { A = A2; W = W2; bias = bias2; Cf = Cf2; Cb = nullptr; }
  __shared__ __align__(16) short As[2][128 * PADK];
  __shared__ __align__(16) short Bs[2][128 * PADK];
  const int isb = rawp ? *rawp : 1;  // output dtype only
  const int n0 = blockIdx.x * 128, m0 = blockIdx.y * 128;
  const int lane = threadIdx.x & 63, wv = threadIdx.x >> 6;
  const int wm = (wv & 1) * 64, wn = (wv >> 1) * 64;
  // staging: thread -> (row 0..127, 16-short half 0..1); 32B A + 32B B per thread
  const int r_ = threadIdx.x >> 1, h_ = threadIdx.x & 1;
  const short* Arow = (const short*)A + (size_t)(m0 + r_) * lda + h_ * 16;
  const short* Brow = (const short*)W + (size_t)(n0 + r_) * ldw + h_ * 16;

  uint4 ra[2][2], rb[2][2];
  auto loadT = [&](int s, int k0) {
    ra[s][0] = *(const uint4*)(Arow + k0);
    ra[s][1] = *(const uint4*)(Arow + k0 + 8);
    rb[s][0] = *(const uint4*)(Brow + k0);
    rb[s][1] = *(const uint4*)(Brow + k0 + 8);
  };
  auto writeT = [&](int s, int buf) {
    short* da = &As[buf][0] + r_ * PADK + h_ * 16;
    *(uint4*)da = ra[s][0];
    *(uint4*)(da + 8) = ra[s][1];
    short* db = &Bs[buf][0] + r_ * PADK + h_ * 16;
    *(uint4*)db = rb[s][0];
    *(uint4*)(db + 8) = rb[s][1];
  };

  f32x4 acc[4][4];
#pragma unroll
  for (int i = 0; i < 4; ++i)
#pragma unroll
    for (int j = 0; j < 4; ++j) acc[i][j] = (f32x4){0.f, 0.f, 0.f, 0.f};

  const int nk = K / 32;  // even, >= 2
  const int rsel = lane & 15, krd = (lane >> 4) * 8;

  auto mfma16 = [&](int buf) {
    frag16 af[4], bfg[4];
#pragma unroll
    for (int i = 0; i < 4; ++i) af[i] = *(const frag16*)&As[buf][(wm + i * 16 + rsel) * PADK + krd];
#pragma unroll
    for (int j = 0; j < 4; ++j) bfg[j] = *(const frag16*)&Bs[buf][(wn + j * 16 + rsel) * PADK + krd];
    __builtin_amdgcn_s_setprio(1);
#pragma unroll
    for (int i = 0; i < 4; ++i)
#pragma unroll
      for (int j = 0; j < 4; ++j)
        acc[i][j] = __builtin_amdgcn_mfma_f32_16x16x32_bf16(af[i], bfg[j], acc[i][j], 0, 0, 0);
    __builtin_amdgcn_s_setprio(0);
  };

  // prologue: tiles 0,1 -> regs; tile 0 -> LDS buf0
  loadT(0, 0);
  loadT(1, 32);
  writeT(0, 0);
  __syncthreads();
  for (int kk = 0; kk < nk; kk += 2) {
    // invariant: buf0 = tile kk, regs set1 = tile kk+1
    if (kk + 2 < nk) loadT(0, 32 * (kk + 2));
    mfma16(0);
    writeT(1, 1);
    __syncthreads();
    if (kk + 3 < nk) loadT(1, 32 * (kk + 3));
    mfma16(1);
    if (kk + 2 < nk) writeT(0, 0);
    __syncthreads();
  }

  const int rq = (lane >> 4) * 4, cq = lane & 15;
#pragma unroll
  for (int j = 0; j < 4; ++j) {
    int cidx = n0 + wn + j * 16 + cq;
    float bv = bias ? bias[cidx] : 0.f;
#pragma unroll
    for (int i = 0; i < 4; ++i) {
      int rbase = m0 + wm + i * 16 + rq;
#pragma unroll
      for (int r = 0; r < 4; ++r) {
        float v = acc[i][j][r] + bv;
        size_t idx = (size_t)(rbase + r) * ldc + cidx;
        if (outmode) {
          if (isb) Cb[idx] = __float2bfloat16(v);
          else Cf[idx] = v;
        } else {
          if (Cf) Cf[idx] = v;
          if (Cb) Cb[idx] = __float2bfloat16(v);
        }
      }
    }
  }
}

// Two-pair norm-accumulate: Spf[b] += concat(hfA,hbA)/||.|| + concat(hfB,hbB)/||.||
// One wave per b (both pairs in one wave -> no RMW race on Spf[b]).
static __device__ __forceinline__ void normacc_row2(
    const bf16* hfA, const bf16* hbA, const bf16* hfB, const bf16* hbB,
    float* __restrict__ Spf, int b, int lane) {
  float vA[10], vB[10];
  float sA = 0.f, sB = 0.f;
#pragma unroll
  for (int s = 0; s < 10; ++s) {
    int d = lane + 64 * s;
    float a = 0.f, c = 0.f;
    if (d < 300) {
      a = __bfloat162float(hfA[d]);
      c = __bfloat162float(hfB[d]);
    } else if (d < 600) {
      a = __bfloat162float(hbA[d - 300]);
      c = __bfloat162float(hbB[d - 300]);
    }
    vA[s] = a; vB[s] = c;
    sA += a * a; sB += c * c;
  }
#pragma unroll
  for (int off = 32; off > 0; off >>= 1) {
    sA += __shfl_xor(sA, off, 64);
    sB += __shfl_xor(sB, off, 64);
  }
  float kA = 1.f / fmaxf(sqrtf(sA), 1e-8f);
  float kB = 1.f / fmaxf(sqrtf(sB), 1e-8f);
  float* dst = Spf + (size_t)b * KC;
#pragma unroll
  for (int s = 0; s < 10; ++s) {
    int d = lane + 64 * s;
    if (d < 600) dst[d] += vA[s] * kA + vB[s] * kB;
  }
}

// Fused bidirectional LSTM timestep. z=0: fwd GEMM (tt=s). z=1: bwd GEMM
// (tt=63-s). z=2: paired normacc (s>=33): fold t1=s-1 (hf plane / Hbst) and
// t2=64-s (Hfst / hb plane). fwd stores hf[t<32] in Hfst, bwd hb[t>=32] in Hbst.
// GEMM tile 128(N)x64(M), 4 waves (wave tile 64x32), padded LDS rows,
// dist-2 paired register prefetch for A (emb gather / h) and B (Wcat rows).
__global__ __launch_bounds__(256) void lstm_step(
    const void* __restrict__ emb, const int* __restrict__ x,
    const bf16* __restrict__ Wcat, const float* __restrict__ bcat,
    bf16* __restrict__ hpad, float* __restrict__ cstate,
    bf16* __restrict__ Hfst, bf16* __restrict__ Hbst, float* __restrict__ Spf,
    int s, const int* __restrict__ flagp) {
  const int pb = s & 1;
  const int lane = threadIdx.x & 63, wv = threadIdx.x >> 6;

  if (blockIdx.z == 2) {  // paired normacc plane (320 blocks)
    if (s >= 33) {
      int bid = blockIdx.x + gridDim.x * blockIdx.y;  // 0..319
      const bf16* hinf = hpad + (size_t)pb * B_ * HP;        // hf[s-1]
      const bf16* hinb = hpad + (size_t)(2 + pb) * B_ * HP;  // hb[64-s]
      const int t1 = s - 1, t2 = 64 - s;
#pragma unroll
      for (int rep = 0; rep < 2; ++rep) {
        int b = bid * 4 + wv + 1280 * rep;
        if (b < B_)
          normacc_row2(hinf + (size_t)b * HP,
                       Hbst + ((size_t)(t1 - 32) * B_ + b) * H_,
                       Hfst + ((size_t)t2 * B_ + b) * H_,
                       hinb + (size_t)b * HP, Spf, b, lane);
      }
    }
    return;
  }

  __shared__ __align__(16) char smem[30720];
  short* As0 = (short*)smem;             // 64xPADK = 5120 B
  short* As1 = (short*)(smem + 5120);
  short* Bs0 = (short*)(smem + 10240);   // 128xPADK = 10240 B
  short* Bs1 = (short*)(smem + 20480);
  float* epi = (float*)smem;             // reused: 64x64 fp32 = 16 KB

  const int dir = blockIdx.z;
  const int tt = dir ? (T_ - 1 - s) : s;
  const int isb = *flagp;
  const bf16* hin = hpad + (size_t)(dir * 2 + pb) * B_ * HP;
  const bf16* Wd = Wcat + (size_t)dir * NP * KC;
  bf16* hout = hpad + (size_t)(dir * 2 + (1 - pb)) * B_ * HP;
  float* cs = cstate + (size_t)dir * B_ * HP;
  const int n0 = blockIdx.x * 128, m0 = blockIdx.y * 64;
  const int wm = (wv & 1) * 32, wn = (wv >> 1) * 64;
  // A staging: thread -> (row 0..63, 8-short chunk 0..3): 16B/thread/tile
  const int r_ = threadIdx.x >> 2, q_ = threadIdx.x & 3;
  // B staging: thread -> (row 0..127, 16-short half 0..1): 32B/thread/tile
  const int r2 = threadIdx.x >> 1, h2 = threadIdx.x & 1;
  const size_t xoff = (size_t)x[(m0 + r_) * T_ + tt] * (size_t)E_;
  const short* es = (const short*)emb;
  const float* ef = (const float*)emb;
  const short* hins = (const short*)hin;
  const short* wrow = (const short*)Wd + (size_t)(n0 + r2) * KC + h2 * 16;

  // two prefetch sets (dist-2)
  uint2 xs[2][2];    // bf16 x-part
  float4 xf[2][2];   // f32 x-part
  uint4 ah[2];       // h-part
  uint4 bw[2][2];    // B rows

  auto loadT = [&](int set, int k0) {
    if (k0 < HP) {
      int c0 = k0 + q_ * 8;
      if (isb) {
        xs[set][0] = (c0 < E_) ? *(const uint2*)(es + xoff + c0) : make_uint2(0u, 0u);
        xs[set][1] = (c0 + 4 < E_) ? *(const uint2*)(es + xoff + c0 + 4) : make_uint2(0u, 0u);
      } else {
        xf[set][0] = (c0 < E_) ? *(const float4*)(ef + xoff + c0) : make_float4(0.f, 0.f, 0.f, 0.f);
        xf[set][1] = (c0 + 4 < E_) ? *(const float4*)(ef + xoff + c0 + 4)
                                   : make_float4(0.f, 0.f, 0.f, 0.f);
      }
    } else {
      ah[set] = *(const uint4*)(hins + (size_t)(m0 + r_) * HP + (k0 - HP) + q_ * 8);
    }
    bw[set][0] = *(const uint4*)(wrow + k0);
    bw[set][1] = *(const uint4*)(wrow + k0 + 8);
  };
  auto writeT = [&](int set, int k0, short* Ad, short* Bd) {
    short* arow = Ad + r_ * PADK + q_ * 8;
    if (k0 < HP) {
      if (isb) {
        *(uint2*)arow = xs[set][0];
        *(uint2*)(arow + 4) = xs[set][1];
      } else {
        *(short4*)arow = f4tob4(xf[set][0]);
        *(short4*)(arow + 4) = f4tob4(xf[set][1]);
      }
    } else {
      *(uint4*)arow = ah[set];
    }
    short* brow = Bd + r2 * PADK + h2 * 16;
    *(uint4*)brow = bw[set][0];
    *(uint4*)(brow + 8) = bw[set][1];
  };

  f32x4 acc[2][4];
#pragma unroll
  for (int i = 0; i < 2; ++i)
#pragma unroll
    for (int j = 0; j < 4; ++j) acc[i][j] = (f32x4){0.f, 0.f, 0.f, 0.f};

  const int rsel = lane & 15, krd = (lane >> 4) * 8;
  const int NKT = KC / 32;  // 20, even

  auto mfma8 = [&](const short* Ap, const short* Bp) {
    frag16 af[2], bfg[4];
#pragma unroll
    for (int i = 0; i < 2; ++i) af[i] = *(const frag16*)&Ap[(wm + i * 16 + rsel) * PADK + krd];
#pragma unroll
    for (int j = 0; j < 4; ++j) bfg[j] = *(const frag16*)&Bp[(wn + j * 16 + rsel) * PADK + krd];
    __builtin_amdgcn_s_setprio(1);
#pragma unroll
    for (int i = 0; i < 2; ++i)
#pragma unroll
      for (int j = 0; j < 4; ++j)
        acc[i][j] = __builtin_amdgcn_mfma_f32_16x16x32_bf16(af[i], bfg[j], acc[i][j], 0, 0, 0);
    __builtin_amdgcn_s_setprio(0);
  };

  loadT(0, 0);
  loadT(1, 32);
  writeT(0, 0, As0, Bs0);
  __syncthreads();
  for (int kk = 0; kk < NKT; kk += 2) {
    // invariant: buf0 = tile kk, set1 = tile kk+1
    if (kk + 2 < NKT) loadT(0, 32 * (kk + 2));
    mfma8(As0, Bs0);
    writeT(1, 32 * (kk + 1), As1, Bs1);
    __syncthreads();
    if (kk + 3 < NKT) loadT(1, 32 * (kk + 3));
    mfma8(As1, Bs1);
    if (kk + 2 < NKT) writeT(0, 32 * (kk + 2), As0, Bs0);
    __syncthreads();
  }

  const int rq = (lane >> 4) * 4, cq = lane & 15;
#pragma unroll
  for (int p = 0; p < 2; ++p) {
    if (wn == p * 64) {
#pragma unroll
      for (int j = 0; j < 4; ++j) {
        int cl = j * 16 + cq;
        float bv = bcat[dir * NP + n0 + p * 64 + cl];
#pragma unroll
        for (int i = 0; i < 2; ++i) {
          int rl = wm + i * 16 + rq;
#pragma unroll
          for (int r = 0; r < 4; ++r) epi[(rl + r) * 64 + cl] = acc[i][j][r] + bv;
        }
      }
    }
    __syncthreads();
    int jbase = (n0 + p * 64) >> 2;
    for (int it = threadIdx.x; it < 64 * 16; it += 256) {
      int rl = it >> 4, jl = it & 15;
      int jg = jbase + jl;
      if (jg < H_) {
        const float* row = epi + rl * 64 + jl * 4;
        float iv = sigf(row[0]);
        float fv = sigf(row[1]);
        float gv = tanhfast(row[2]);
        float ov = sigf(row[3]);
        int b = m0 + rl;
        float c = fv * cs[(size_t)b * HP + jg] + iv * gv;
        float h = ov * tanhfast(c);
        cs[(size_t)b * HP + jg] = c;
        bf16 hb = __float2bfloat16(h);
        hout[(size_t)b * HP + jg] = hb;
        if (dir) {
          if (tt >= 32) Hbst[((size_t)(tt - 32) * B_ + b) * H_ + jg] = hb;
        } else if (tt < 32) {
          Hfst[((size_t)tt * B_ + b) * H_ + jg] = hb;
        }
      }
    }
    __syncthreads();
  }
}

// Cleanup pairs t=63 (hf: fwd hout plane 0, hb: Hbst[31]) and t=0
// (hf: Hfst[0], hb: bwd hout plane 2) after the fused loop.
__global__ __launch_bounds__(256) void normacc_fin(const bf16* __restrict__ hpad,
                                                   const bf16* __restrict__ Hfst,
                                                   const bf16* __restrict__ Hbst,
                                                   float* __restrict__ Spf) {
  int b = blockIdx.x * 4 + (threadIdx.x >> 6);
  int lane = threadIdx.x & 63;
  normacc_row2(hpad + (size_t)b * HP,
               Hbst + ((size_t)31 * B_ + b) * H_,
               Hfst + (size_t)b * H_,
               hpad + (size_t)2 * B_ * HP + (size_t)b * HP, Spf, b, lane);
}

// Build gate-interleaved padded weights + bias for both dirs (dtype-flexible).
__global__ void prep_wcat(const void* __restrict__ Wih_f, const void* __restrict__ Whh_f,
                          const void* __restrict__ bih_f, const void* __restrict__ bhh_f,
                          const void* __restrict__ Wih_b, const void* __restrict__ Whh_b,
                          const void* __restrict__ bih_b, const void* __restrict__ bhh_b,
                          bf16* __restrict__ Wcat, float* __restrict__ bcat,
                          const int* __restrict__ flagp) {
  int i = blockIdx.x * 256 + threadIdx.x;
  if (i >= 2 * NP * KC) return;
  const int isb = *flagp;
  int k = i % KC;
  int n = (i / KC) % NP;
  int dir = i / (KC * NP);
  int j = n >> 2, q = n & 3;
  const void* Wih = dir ? Wih_b : Wih_f;
  const void* Whh = dir ? Whh_b : Whh_f;
  float v = 0.f;
  if (j < H_) {
    int row = q * H_ + j;
    if (k < E_) v = ldraw(Wih, (size_t)row * E_ + k, isb);
    else if (k >= HP && k < HP + H_) v = ldraw(Whh, (size_t)row * H_ + (k - HP), isb);
  }
  Wcat[i] = __float2bfloat16(v);
  if (k == 0) {
    const void* bih = dir ? bih_b : bih_f;
    const void* bhh = dir ? bhh_b : bhh_f;
    bcat[dir * NP + n] =
        (j < H_) ? (ldraw(bih, q * H_ + j, isb) + ldraw(bhh, q * H_ + j, isb)) : 0.f;
  }
}

// Normalized label embeddings, K-padded 600->640 (dtype-flexible).
__global__ __launch_bounds__(256) void labelnorm(const void* __restrict__ L,
                                                 bf16* __restrict__ lnp,
                                                 const int* __restrict__ flagp) {
  int l = blockIdx.x, tid = threadIdx.x;
  const int isb = *flagp;
  __shared__ float red[4];
  float v[3];
  float ss = 0.f;
#pragma unroll
  for (int s = 0; s < 3; ++s) {
    int d = tid + 256 * s;
    v[s] = (d < 600) ? ldraw(L, (size_t)l * 600 + d, isb) : 0.f;
    ss += v[s] * v[s];
  }
  for (int off = 32; off > 0; off >>= 1) ss += __shfl_down(ss, off, 64);
  if ((tid & 63) == 0) red[tid >> 6] = ss;
  __syncthreads();
  float scale = 1.f / fmaxf(sqrtf(red[0] + red[1] + red[2] + red[3]), 1e-8f);
#pragma unroll
  for (int s = 0; s < 3; ++s) {
    int d = tid + 256 * s;
    if (d < KC) lnp[(size_t)l * KC + d] = __float2bfloat16(v[s] * scale);
  }
}

__global__ void spcvt(const float* __restrict__ Spf, bf16* __restrict__ Sp) {
  int i = blockIdx.x * 256 + threadIdx.x;
  Sp[i] = __float2bfloat16(Spf[i]);
}

// Wt[l][n][k] = ggc_weight[l][k][n] (dtype-flexible source)
__global__ void transpose_ggc(const void* __restrict__ W, bf16* __restrict__ Wt,
                              const int* __restrict__ flagp) {
  int i = blockIdx.x * 256 + threadIdx.x;
  const int isb = *flagp;
  int k = i & 1023, n = (i >> 10) & 1023, l = i >> 20;
  size_t src = ((size_t)l << 20) | ((size_t)k << 10) | (size_t)n;
  Wt[i] = __float2bfloat16(ldraw(W, src, isb));
}

// raw (f32 or bf16) -> bf16 weight conversion
__global__ void w2bf(const void* __restrict__ src, bf16* __restrict__ dst, int n,
                     const int* __restrict__ flagp) {
  int i = blockIdx.x * 256 + threadIdx.x;
  if (i < n) dst[i] = __float2bfloat16(ldraw(src, i, *flagp));
}
// raw bias -> f32
__global__ void b2f32(const void* __restrict__ src, float* __restrict__ dst, int n,
                      const int* __restrict__ flagp) {
  int i = blockIdx.x * 256 + threadIdx.x;
  if (i < n) dst[i] = ldraw(src, i, *flagp);
}

__global__ void zero_u4(uint4* __restrict__ p, int n16) {
  int i = blockIdx.x * 256 + threadIdx.x;
  if (i < n16) p[i] = make_uint4(0u, 0u, 0u, 0u);
}

// Dense adjacency counts: cnt[d][s] = #edges s->d (int atomics, 65536 total).
__global__ void edge_cnt(const int* __restrict__ ei, int* __restrict__ cnt) {
  int e = blockIdx.x * 256 + threadIdx.x;
  if (e < NE_) {
    int s = ei[e], d = ei[NE_ + e];
    atomicAdd(&cnt[(size_t)d * B_ + s], 1);
  }
}
__global__ void cnt2bf(const int* __restrict__ cnt, bf16* __restrict__ A) {
  int i = blockIdx.x * 256 + threadIdx.x;  // 4M
  A[i] = __float2bfloat16((float)cnt[i]);
}

__global__ void gru_ew(const float* __restrict__ gi, const float* __restrict__ gh,
                       float* __restrict__ h, bf16* __restrict__ hb16) {
  int i = blockIdx.x * 256 + threadIdx.x;
  int b = i >> 10, j = i & 1023;
  const float* gib = gi + (size_t)b * 3072;
  const float* ghb = gh + (size_t)b * 3072;
  float r = sigf(gib[j] + ghb[j]);
  float z = sigf(gib[1024 + j] + ghb[1024 + j]);
  float n = tanhfast(gib[2048 + j] + r * ghb[2048 + j]);
  float hv = (1.f - z) * n + z * h[i];
  h[i] = hv;
  hb16[i] = __float2bfloat16(hv);
}

__global__ void sentinel(bf16* __restrict__ o, int n, float v) {
  int i = blockIdx.x * 256 + threadIdx.x;
  if (i < n) o[i] = __float2bfloat16(v);
}

extern "C" void kernel_launch(void* const* d_in, const int* in_sizes, int n_in,
                              void* d_out, int out_size, void* d_ws, size_t ws_size,
                              hipStream_t stream) {
  const int* x = (const int*)d_in[0];
  const int* ei = (const int*)d_in[1];
  const void* emb = d_in[2];
  const void* Wih_f = d_in[3];
  const void* Whh_f = d_in[4];
  const void* bih_f = d_in[5];
  const void* bhh_f = d_in[6];
  const void* Wih_b = d_in[7];
  const void* Whh_b = d_in[8];
  const void* bih_b = d_in[9];
  const void* bhh_b = d_in[10];
  const void* label = d_in[11];
  const void* ggcw = d_in[12];
  const void* gWih = d_in[13];
  const void* gWhh = d_in[14];
  const void* gbih = d_in[15];
  const void* gbhh = d_in[16];
  const void* projW = d_in[17];
  const void* projb = d_in[18];
  (void)in_sizes; (void)n_in;

  const size_t NEED = (size_t)112 * 1024 * 1024;
  if (ws_size < NEED) {
    float v = 100.f + (float)(ws_size >> 24);
    sentinel<<<(out_size + 255) / 256, 256, 0, stream>>>((bf16*)d_out, out_size, v);
    return;
  }

  char* w = (char*)d_ws;
  size_t off = 0;
  auto alloc = [&](size_t bytes) {
    char* p = w + off;
    off += (bytes + 255) & ~(size_t)255;
    return p;
  };
  // ---- persistent (~11.2 MB) ----
  int* dflag = (int*)alloc(256);
  bf16* Wcat = (bf16*)alloc((size_t)2 * NP * KC * 2);
  float* bcat = (float*)alloc((size_t)2 * NP * 4);
  bf16* lnp = (bf16*)alloc((size_t)C_ * KC * 2);
  bf16* ggct = (bf16*)alloc((size_t)2 * C_ * C_ * 2);
  bf16* Sp = (bf16*)alloc((size_t)B_ * KC * 2);
  const size_t phase_base = off;
  // ---- phase 1 (LSTM): ~96.5 MB ----
  float* Spf = (float*)alloc((size_t)B_ * KC * 4);
  bf16* hpad = (bf16*)alloc((size_t)4 * B_ * HP * 2);
  float* cst = (float*)alloc((size_t)2 * B_ * HP * 4);
  bf16* Hfst = (bf16*)alloc((size_t)32 * B_ * H_ * 2);  // hf[t] for t=0..31
  bf16* Hbst = (bf16*)alloc((size_t)32 * B_ * H_ * 2);  // hb[t] for t=32..63
  // ---- phase 2 (graph): ~94 MB, aliases phase 1 ----
  off = phase_base;
  float* hbuf = (float*)alloc((size_t)B_ * C_ * 4);
  bf16* hb16 = (bf16*)alloc((size_t)B_ * C_ * 2);
  bf16* m1t = (bf16*)alloc((size_t)C_ * B_ * 2);     // m transposed [c][s]
  bf16* aggb = (bf16*)alloc((size_t)B_ * C_ * 2);
  bf16* Acnt = (bf16*)alloc((size_t)B_ * B_ * 2);    // dense adjacency counts
  float* gi = (float*)alloc((size_t)B_ * 3072 * 4);  // cnt(i32, 16MB) aliases head of gi
  float* gh = (float*)alloc((size_t)B_ * 3072 * 4);
  bf16* gWihb = (bf16*)alloc((size_t)3072 * C_ * 2);  // pre-converted bf16 weights
  bf16* gWhhb = (bf16*)alloc((size_t)3072 * C_ * 2);
  bf16* projWb = (bf16*)alloc((size_t)C_ * C_ * 2);
  float* gbihf = (float*)alloc(3072 * 4);
  float* gbhhf = (float*)alloc(3072 * 4);
  float* projbf = (float*)alloc(C_ * 4);
  int* cnt = (int*)gi;

  // ---- dtype detection + prep ----
  detect_dtype<<<1, 256, 0, stream>>>((const unsigned short*)emb, dflag);
  prep_wcat<<<(2 * NP * KC) / 256, 256, 0, stream>>>(Wih_f, Whh_f, bih_f, bhh_f,
                                                     Wih_b, Whh_b, bih_b, bhh_b, Wcat, bcat, dflag);
  labelnorm<<<C_, 256, 0, stream>>>(label, lnp, dflag);
  transpose_ggc<<<(2 * C_ * C_) / 256, 256, 0, stream>>>(ggcw, ggct, dflag);
  zero_u4<<<(4 * B_ * HP * 2 / 16 + 255) / 256, 256, 0, stream>>>((uint4*)hpad, 4 * B_ * HP * 2 / 16);
  zero_u4<<<(2 * B_ * HP * 4 / 16 + 255) / 256, 256, 0, stream>>>((uint4*)cst, 2 * B_ * HP * 4 / 16);
  zero_u4<<<(B_ * KC * 4 / 16 + 255) / 256, 256, 0, stream>>>((uint4*)Spf, B_ * KC * 4 / 16);

  // ---- phase 1: fused bidir LSTM, 64 sequential dispatches ----
  // z=0 fwd GEMM, z=1 bwd GEMM, z=2 paired normacc (active s>=33).
  for (int s = 0; s < T_; ++s)
    lstm_step<<<dim3(NP / 128, B_ / 64, 3), 256, 0, stream>>>(emb, x, Wcat, bcat, hpad, cst,
                                                              Hfst, Hbst, Spf, s, dflag);
  normacc_fin<<<B_ / 4, 256, 0, stream>>>(hpad, Hfst, Hbst, Spf);
  spcvt<<<(B_ * KC) / 256, 256, 0, stream>>>(Spf, Sp);

  // ---- phase 2 prep: convert raw GRU/proj weights to bf16, biases to f32 ----
  w2bf<<<(3072 * C_) / 256, 256, 0, stream>>>(gWih, gWihb, 3072 * C_, dflag);
  w2bf<<<(3072 * C_) / 256, 256, 0, stream>>>(gWhh, gWhhb, 3072 * C_, dflag);
  w2bf<<<(C_ * C_) / 256, 256, 0, stream>>>(projW, projWb, C_ * C_, dflag);
  b2f32<<<12, 256, 0, stream>>>(gbih, gbihf, 3072, dflag);
  b2f32<<<12, 256, 0, stream>>>(gbhh, gbhhf, 3072, dflag);
  b2f32<<<4, 256, 0, stream>>>(projb, projbf, C_, dflag);

  // ---- phase 2: label scores + GatedGraphConv (dense-adjacency GEMM) + proj ----
  gemm_bt<<<dim3(C_ / 128, B_ / 128), 256, 0, stream>>>(Sp, KC, lnp, KC, nullptr,
                                                        hbuf, hb16, C_, KC, nullptr, 0,
                                                        nullptr, nullptr, nullptr, nullptr);
  // adjacency counts (built once, reused by both layers)
  zero_u4<<<(B_ * B_ * 4 / 16 + 255) / 256, 256, 0, stream>>>((uint4*)cnt, B_ * B_ * 4 / 16);
  edge_cnt<<<NE_ / 256, 256, 0, stream>>>(ei, cnt);
  cnt2bf<<<(B_ * B_) / 256, 256, 0, stream>>>(cnt, Acnt);
  for (int l = 0; l < 2; ++l) {
    // m1t[c][s] = sum_k ggcw[l][k][c] * h[s][k]   (A/W roles swapped)
    gemm_bt<<<dim3(B_ / 128, C_ / 128), 256, 0, stream>>>(ggct + (size_t)l * C_ * C_, C_,
                                                          hb16, C_, nullptr,
                                                          nullptr, m1t, B_, C_, nullptr, 0,
                                                          nullptr, nullptr, nullptr, nullptr);
    // agg[d][c] = sum_s Acnt[d][s] * m1t[c][s]
    gemm_bt<<<dim3(C_ / 128, B_ / 128), 256, 0, stream>>>(Acnt, B_, m1t, B_, nullptr,
                                                          nullptr, aggb, C_, B_, nullptr, 0,
                                                          nullptr, nullptr, nullptr, nullptr);
    // gi and gh batched into one dispatch (z=0: gi, z=1: gh)
    gemm_bt<<<dim3(3072 / 128, B_ / 128, 2), 256, 0, stream>>>(aggb, C_, gWihb, C_, gbihf,
                                                               gi, nullptr, 3072, C_, nullptr, 0,
                                                               hb16, gWhhb, gbhhf, gh);
    gru_ew<<<(B_ * C_) / 256, 256, 0, stream>>>(gi, gh, hbuf, hb16);
  }
  gemm_bt<<<dim3(C_ / 128, B_ / 128), 256, 0, stream>>>(hb16, C_, projWb, C_, projbf,
                                                        (float*)d_out, (bf16*)d_out, C_, C_,
                                                        dflag, 1,
                                                        nullptr, nullptr, nullptr, nullptr);
}

// Round 6
// 2271.446 us; speedup vs baseline: 2.1351x; 2.1351x over previous
//
#include <hip/hip_runtime.h>
#include <hip/hip_bf16.h>
#include <stdint.h>

typedef __hip_bfloat16 bf16;
typedef __attribute__((ext_vector_type(8))) short frag16;
typedef __attribute__((ext_vector_type(4))) float f32x4;

#define B_ 2048
#define T_ 64
#define E_ 300
#define H_ 300
#define C_ 1024
#define V_ 50000
#define NE_ 65536
#define HP 320     // padded E/H half of concat-K
#define KC 640     // padded concat K (320 x + 320 h)
#define NP 1280    // padded 4H, gate-interleaved n = 4*j + q

static __device__ __forceinline__ float sigf(float x) {
  x = fminf(fmaxf(x, -30.f), 30.f);
  return 1.f / (1.f + __expf(-x));
}
static __device__ __forceinline__ float tanhfast(float x) {
  x = fminf(fmaxf(x, -15.f), 15.f);
  float e = __expf(2.f * x);
  return (e - 1.f) / (e + 1.f);
}
static __device__ __forceinline__ float ldraw(const void* p, size_t i, int isb) {
  return isb ? __bfloat162float(((const bf16*)p)[i]) : ((const float*)p)[i];
}
static __device__ __forceinline__ short b2s(bf16 b) {
  short s; __builtin_memcpy(&s, &b, 2); return s;
}
static __device__ __forceinline__ short4 f4tob4(float4 v) {
  return make_short4(b2s(__float2bfloat16(v.x)), b2s(__float2bfloat16(v.y)),
                     b2s(__float2bfloat16(v.z)), b2s(__float2bfloat16(v.w)));
}

// Direct global->LDS 16B per lane. LDS dest must be wave-uniform (HW uses
// readfirstlane); lane i lands at base + i*16B. Global source is per-lane.
// LDS AS3 pointer via uintptr truncation (HK global_to_shared pattern).
static __device__ __forceinline__ void g2l16(const void* g, void* l) {
  __builtin_amdgcn_global_load_lds(
      (const __attribute__((address_space(1))) void*)(uintptr_t)g,
      (__attribute__((address_space(3))) void*)(uintptr_t)l, 16, 0, 0);
}

// Input dtype detector: bit14 of low half-word is 0 in bf16 world (|v|<2),
// ~Bernoulli(0.5) in f32 world (mantissa bits).
__global__ void detect_dtype(const unsigned short* __restrict__ e2, int* __restrict__ flag) {
  __shared__ int red[4];
  int tid = threadIdx.x;
  int ones = 0;
#pragma unroll
  for (int s = 0; s < 16; ++s) ones += (e2[2 * (tid * 16 + s)] >> 14) & 1;
  for (int off = 32; off > 0; off >>= 1) ones += __shfl_down(ones, off, 64);
  if ((tid & 63) == 0) red[tid >> 6] = ones;
  __syncthreads();
  if (tid == 0) {
    int tot = red[0] + red[1] + red[2] + red[3];
    *flag = (tot < 1024) ? 1 : 0;  // 1 = bf16 inputs, 0 = f32 inputs
  }
}

// C[m][n] = sum_k A[m][k]*W[n][k] (+bias[n]); M,N mult of 128, K of 32.
// A,W bf16 (phase-2 raw weights pre-converted), bias f32. m97 structure:
// single LDS buffer, global_load_lds width-16 staging, 2 barriers/tile.
// gridDim.z==2: z==1 uses (A2,W2,bias2,Cf2) (batches GRU gate GEMMs).
// outmode=1: d_out in raw dtype per *rawp.
__global__ __launch_bounds__(256) void gemm_bt(
    const bf16* A, int lda, const bf16* W, int ldw, const float* bias,
    float* Cf, bf16* Cb, int ldc, int K,
    const int* __restrict__ rawp, int outmode,
    const bf16* A2, const bf16* W2, const float* bias2, float* Cf2) {
  if (blockIdx.z) { A = A2; W = W2; bias = bias2; Cf = Cf2; Cb = nullptr; }
  __shared__ __align__(16) short As[128 * 32];
  __shared__ __align__(16) short Bs[128 * 32];
  const int isb = rawp ? *rawp : 1;  // output dtype only
  const int n0 = blockIdx.x * 128, m0 = blockIdx.y * 128;
  const int lane = threadIdx.x & 63, wv = threadIdx.x >> 6;
  const int wm = (wv & 1) * 64, wn = (wv >> 1) * 64;
  // gload geometry: wave wv covers 32 rows (2 calls x 16); lane -> (row,chunk)
  const int gr = lane >> 2;          // row within 16-row call group
  const int gc = (lane & 3) * 8;     // short col within 32-k tile
  const short* pA0 = (const short*)A + (size_t)(m0 + wv * 32 + gr) * lda + gc;
  const short* pA1 = pA0 + (size_t)16 * lda;
  const short* pB0 = (const short*)W + (size_t)(n0 + wv * 32 + gr) * ldw + gc;
  const short* pB1 = pB0 + (size_t)16 * ldw;
  short* lA = As + wv * 1024;  // wave-uniform LDS bases
  short* lB = Bs + wv * 1024;

  f32x4 acc[4][4];
#pragma unroll
  for (int i = 0; i < 4; ++i)
#pragma unroll
    for (int j = 0; j < 4; ++j) acc[i][j] = (f32x4){0.f, 0.f, 0.f, 0.f};

  const int krd = (lane >> 4) * 8;
  const int rsel = lane & 15;
  for (int k0 = 0; k0 < K; k0 += 32) {
    g2l16(pA0 + k0, lA);
    g2l16(pA1 + k0, lA + 512);
    g2l16(pB0 + k0, lB);
    g2l16(pB1 + k0, lB + 512);
    __syncthreads();
    frag16 af[4], bfg[4];
#pragma unroll
    for (int i = 0; i < 4; ++i) af[i] = *(const frag16*)&As[(wm + i * 16 + rsel) * 32 + krd];
#pragma unroll
    for (int i = 0; i < 4; ++i) bfg[i] = *(const frag16*)&Bs[(wn + i * 16 + rsel) * 32 + krd];
#pragma unroll
    for (int i = 0; i < 4; ++i)
#pragma unroll
      for (int j = 0; j < 4; ++j)
        acc[i][j] = __builtin_amdgcn_mfma_f32_16x16x32_bf16(af[i], bfg[j], acc[i][j], 0, 0, 0);
    __syncthreads();
  }
  const int rq = (lane >> 4) * 4, cq = lane & 15;
#pragma unroll
  for (int j = 0; j < 4; ++j) {
    int cidx = n0 + wn + j * 16 + cq;
    float bv = bias ? bias[cidx] : 0.f;
#pragma unroll
    for (int i = 0; i < 4; ++i) {
      int rbase = m0 + wm + i * 16 + rq;
#pragma unroll
      for (int r = 0; r < 4; ++r) {
        float v = acc[i][j][r] + bv;
        size_t idx = (size_t)(rbase + r) * ldc + cidx;
        if (outmode) {
          if (isb) Cb[idx] = __float2bfloat16(v);
          else Cf[idx] = v;
        } else {
          if (Cf) Cf[idx] = v;
          if (Cb) Cb[idx] = __float2bfloat16(v);
        }
      }
    }
  }
}

// Two-pair norm-accumulate: Spf[b] += concat(hfA,hbA)/||.|| + concat(hfB,hbB)/||.||
// One wave per b (both pairs in one wave -> no RMW race on Spf[b]).
static __device__ __forceinline__ void normacc_row2(
    const bf16* hfA, const bf16* hbA, const bf16* hfB, const bf16* hbB,
    float* __restrict__ Spf, int b, int lane) {
  float vA[10], vB[10];
  float sA = 0.f, sB = 0.f;
#pragma unroll
  for (int s = 0; s < 10; ++s) {
    int d = lane + 64 * s;
    float a = 0.f, c = 0.f;
    if (d < 300) {
      a = __bfloat162float(hfA[d]);
      c = __bfloat162float(hfB[d]);
    } else if (d < 600) {
      a = __bfloat162float(hbA[d - 300]);
      c = __bfloat162float(hbB[d - 300]);
    }
    vA[s] = a; vB[s] = c;
    sA += a * a; sB += c * c;
  }
#pragma unroll
  for (int off = 32; off > 0; off >>= 1) {
    sA += __shfl_xor(sA, off, 64);
    sB += __shfl_xor(sB, off, 64);
  }
  float kA = 1.f / fmaxf(sqrtf(sA), 1e-8f);
  float kB = 1.f / fmaxf(sqrtf(sB), 1e-8f);
  float* dst = Spf + (size_t)b * KC;
#pragma unroll
  for (int s = 0; s < 10; ++s) {
    int d = lane + 64 * s;
    if (d < 600) dst[d] += vA[s] * kA + vB[s] * kB;
  }
}

// Fused bidirectional LSTM timestep. z=0: fwd GEMM (tt=s). z=1: bwd GEMM
// (tt=63-s). z=2: paired normacc (s>=33): fold t1=s-1 (hf plane / Hbst) and
// t2=64-s (Hfst / hb plane). fwd stores hf[t<32] in Hfst, bwd hb[t>=32] in Hbst.
// GEMM tile 128(N)x64(M), m97 structure: single LDS buffer, global_load_lds
// staging (B rows from Wcat, h-half rows from hpad, x-half per-lane emb gather
// with embtail[V][32] handling the 288..319 pad tile). f32-emb falls back to
// reg-staging for the x-half only.
__global__ __launch_bounds__(256) void lstm_step(
    const void* __restrict__ emb, const bf16* __restrict__ embtail,
    const int* __restrict__ x,
    const bf16* __restrict__ Wcat, const float* __restrict__ bcat,
    bf16* __restrict__ hpad, float* __restrict__ cstate,
    bf16* __restrict__ Hfst, bf16* __restrict__ Hbst, float* __restrict__ Spf,
    int s, const int* __restrict__ flagp) {
  const int pb = s & 1;
  const int lane = threadIdx.x & 63, wv = threadIdx.x >> 6;

  if (blockIdx.z == 2) {  // paired normacc plane (320 blocks)
    if (s >= 33) {
      int bid = blockIdx.x + gridDim.x * blockIdx.y;  // 0..319
      const bf16* hinf = hpad + (size_t)pb * B_ * HP;        // hf[s-1]
      const bf16* hinb = hpad + (size_t)(2 + pb) * B_ * HP;  // hb[64-s]
      const int t1 = s - 1, t2 = 64 - s;
#pragma unroll
      for (int rep = 0; rep < 2; ++rep) {
        int b = bid * 4 + wv + 1280 * rep;
        if (b < B_)
          normacc_row2(hinf + (size_t)b * HP,
                       Hbst + ((size_t)(t1 - 32) * B_ + b) * H_,
                       Hfst + ((size_t)t2 * B_ + b) * H_,
                       hinb + (size_t)b * HP, Spf, b, lane);
      }
    }
    return;
  }

  __shared__ __align__(16) char smem[16384];
  short* As = (short*)smem;           // 64x32 = 4 KB
  short* Bs = (short*)(smem + 4096);  // 128x32 = 8 KB
  float* epi = (float*)smem;          // reused: 64x64 fp32 = 16 KB

  const int dir = blockIdx.z;
  const int tt = dir ? (T_ - 1 - s) : s;
  const int isb = *flagp;
  const bf16* hin = hpad + (size_t)(dir * 2 + pb) * B_ * HP;
  const bf16* Wd = Wcat + (size_t)dir * NP * KC;
  bf16* hout = hpad + (size_t)(dir * 2 + (1 - pb)) * B_ * HP;
  float* cs = cstate + (size_t)dir * B_ * HP;
  const int n0 = blockIdx.x * 128, m0 = blockIdx.y * 64;
  const int wm = (wv & 1) * 32, wn = (wv >> 1) * 64;
  // gload geometry
  const int gr = lane >> 2;        // row within 16-row call group
  const int gc = (lane & 3) * 8;   // short col within 32-k tile
  const int arow = m0 + wv * 16 + gr;            // A row owned by this lane
  const int tok = x[arow * T_ + tt];             // emb token for this row
  const short* es = (const short*)emb;
  const float* ef = (const float*)emb;
  const short* px = es + (size_t)tok * E_ + gc;              // bf16 emb row
  const short* ptail = (const short*)embtail + (size_t)tok * 32 + gc;
  const short* ph = (const short*)hin + (size_t)arow * HP + gc;
  const short* pB0 = (const short*)Wd + (size_t)(n0 + wv * 32 + gr) * KC + gc;
  const short* pB1 = pB0 + (size_t)16 * KC;
  short* lA = As + wv * 512;   // wave-uniform LDS bases (16 rows/call)
  short* lB = Bs + wv * 1024;

  f32x4 acc[2][4];
#pragma unroll
  for (int i = 0; i < 2; ++i)
#pragma unroll
    for (int j = 0; j < 4; ++j) acc[i][j] = (f32x4){0.f, 0.f, 0.f, 0.f};

  const int rsel = lane & 15, krd = (lane >> 4) * 8;
  for (int kk = 0; kk < KC / 32; ++kk) {
    const int k0 = kk * 32;
    if (k0 < HP) {
      if (isb) {
        // chunks never straddle E_ for k0<288 (max end 256+24+8=288);
        // k0==288 reads the prepadded tail table (cols 288..319).
        g2l16(k0 == 288 ? ptail : (px + k0), lA);
      } else {
        // f32 fallback: reg-stage + convert (4-elem predication, 300%4==0)
        int c0 = k0 + gc;
        float4 fa = (c0 < E_) ? *(const float4*)(ef + (size_t)tok * E_ + c0)
                              : make_float4(0.f, 0.f, 0.f, 0.f);
        float4 fb = (c0 + 4 < E_) ? *(const float4*)(ef + (size_t)tok * E_ + c0 + 4)
                                  : make_float4(0.f, 0.f, 0.f, 0.f);
        short* d = As + (wv * 16 + gr) * 32 + gc;
        *(short4*)d = f4tob4(fa);
        *(short4*)(d + 4) = f4tob4(fb);
      }
    } else {
      g2l16(ph + (k0 - HP), lA);  // hpad cols 300..319 are persistent zeros
    }
    g2l16(pB0 + k0, lB);
    g2l16(pB1 + k0, lB + 512);
    __syncthreads();
    frag16 af[2], bfg[4];
#pragma unroll
    for (int i = 0; i < 2; ++i) af[i] = *(const frag16*)&As[(wm + i * 16 + rsel) * 32 + krd];
#pragma unroll
    for (int j = 0; j < 4; ++j) bfg[j] = *(const frag16*)&Bs[(wn + j * 16 + rsel) * 32 + krd];
#pragma unroll
    for (int i = 0; i < 2; ++i)
#pragma unroll
      for (int j = 0; j < 4; ++j)
        acc[i][j] = __builtin_amdgcn_mfma_f32_16x16x32_bf16(af[i], bfg[j], acc[i][j], 0, 0, 0);
    __syncthreads();
  }

  const int rq = (lane >> 4) * 4, cq = lane & 15;
#pragma unroll
  for (int p = 0; p < 2; ++p) {
    if (wn == p * 64) {
#pragma unroll
      for (int j = 0; j < 4; ++j) {
        int cl = j * 16 + cq;
        float bv = bcat[dir * NP + n0 + p * 64 + cl];
#pragma unroll
        for (int i = 0; i < 2; ++i) {
          int rl = wm + i * 16 + rq;
#pragma unroll
          for (int r = 0; r < 4; ++r) epi[(rl + r) * 64 + cl] = acc[i][j][r] + bv;
        }
      }
    }
    __syncthreads();
    int jbase = (n0 + p * 64) >> 2;
    for (int it = threadIdx.x; it < 64 * 16; it += 256) {
      int rl = it >> 4, jl = it & 15;
      int jg = jbase + jl;
      if (jg < H_) {
        const float* row = epi + rl * 64 + jl * 4;
        float iv = sigf(row[0]);
        float fv = sigf(row[1]);
        float gv = tanhfast(row[2]);
        float ov = sigf(row[3]);
        int b = m0 + rl;
        float c = fv * cs[(size_t)b * HP + jg] + iv * gv;
        float h = ov * tanhfast(c);
        cs[(size_t)b * HP + jg] = c;
        bf16 hb = __float2bfloat16(h);
        hout[(size_t)b * HP + jg] = hb;
        if (dir) {
          if (tt >= 32) Hbst[((size_t)(tt - 32) * B_ + b) * H_ + jg] = hb;
        } else if (tt < 32) {
          Hfst[((size_t)tt * B_ + b) * H_ + jg] = hb;
        }
      }
    }
    __syncthreads();
  }
}

// Cleanup pairs t=63 (hf: fwd hout plane 0, hb: Hbst[31]) and t=0
// (hf: Hfst[0], hb: bwd hout plane 2) after the fused loop.
__global__ __launch_bounds__(256) void normacc_fin(const bf16* __restrict__ hpad,
                                                   const bf16* __restrict__ Hfst,
                                                   const bf16* __restrict__ Hbst,
                                                   float* __restrict__ Spf) {
  int b = blockIdx.x * 4 + (threadIdx.x >> 6);
  int lane = threadIdx.x & 63;
  normacc_row2(hpad + (size_t)b * HP,
               Hbst + ((size_t)31 * B_ + b) * H_,
               Hfst + (size_t)b * H_,
               hpad + (size_t)2 * B_ * HP + (size_t)b * HP, Spf, b, lane);
}

// Merged prep: blocks [0,1024) = labelnorm; blocks >=1024 = elementwise
// {prep_wcat | transpose_ggc | embtail} by index range.
__global__ void prep_all(const void* __restrict__ Wih_f, const void* __restrict__ Whh_f,
                         const void* __restrict__ bih_f, const void* __restrict__ bhh_f,
                         const void* __restrict__ Wih_b, const void* __restrict__ Whh_b,
                         const void* __restrict__ bih_b, const void* __restrict__ bhh_b,
                         const void* __restrict__ label, const void* __restrict__ ggcw,
                         const void* __restrict__ emb,
                         bf16* __restrict__ Wcat, float* __restrict__ bcat,
                         bf16* __restrict__ lnp, bf16* __restrict__ ggct,
                         bf16* __restrict__ embtail,
                         const int* __restrict__ flagp) {
  const int isb = *flagp;
  if (blockIdx.x < 1024) {  // labelnorm, l = blockIdx.x
    int l = blockIdx.x, tid = threadIdx.x;
    __shared__ float red[4];
    float v[3];
    float ss = 0.f;
#pragma unroll
    for (int s = 0; s < 3; ++s) {
      int d = tid + 256 * s;
      v[s] = (d < 600) ? ldraw(label, (size_t)l * 600 + d, isb) : 0.f;
      ss += v[s] * v[s];
    }
    for (int off = 32; off > 0; off >>= 1) ss += __shfl_down(ss, off, 64);
    if ((tid & 63) == 0) red[tid >> 6] = ss;
    __syncthreads();
    float scale = 1.f / fmaxf(sqrtf(red[0] + red[1] + red[2] + red[3]), 1e-8f);
#pragma unroll
    for (int s = 0; s < 3; ++s) {
      int d = tid + 256 * s;
      if (d < KC) lnp[(size_t)l * KC + d] = __float2bfloat16(v[s] * scale);
    }
    return;
  }
  int i = (blockIdx.x - 1024) * 256 + threadIdx.x;
  if (i < 2 * NP * KC) {  // prep_wcat
    int k = i % KC;
    int n = (i / KC) % NP;
    int dir = i / (KC * NP);
    int j = n >> 2, q = n & 3;
    const void* Wih = dir ? Wih_b : Wih_f;
    const void* Whh = dir ? Whh_b : Whh_f;
    float v = 0.f;
    if (j < H_) {
      int row = q * H_ + j;
      if (k < E_) v = ldraw(Wih, (size_t)row * E_ + k, isb);
      else if (k >= HP && k < HP + H_) v = ldraw(Whh, (size_t)row * H_ + (k - HP), isb);
    }
    Wcat[i] = __float2bfloat16(v);
    if (k == 0) {
      const void* bih = dir ? bih_b : bih_f;
      const void* bhh = dir ? bhh_b : bhh_f;
      bcat[dir * NP + n] =
          (j < H_) ? (ldraw(bih, q * H_ + j, isb) + ldraw(bhh, q * H_ + j, isb)) : 0.f;
    }
    return;
  }
  i -= 2 * NP * KC;
  if (i < 2 * C_ * C_) {  // transpose_ggc: Wt[l][n][k] = ggc[l][k][n]
    int k = i & 1023, n = (i >> 10) & 1023, l = i >> 20;
    size_t src = ((size_t)l << 20) | ((size_t)k << 10) | (size_t)n;
    ggct[i] = __float2bfloat16(ldraw(ggcw, src, isb));
    return;
  }
  i -= 2 * C_ * C_;
  if (i < V_ * 32) {  // embtail[v][c] = (c<12) ? emb[v][288+c] : 0
    int v = i >> 5, c = i & 31;
    float val = (c < E_ - 288) ? ldraw(emb, (size_t)v * E_ + 288 + c, isb) : 0.f;
    embtail[i] = __float2bfloat16(val);
  }
}

// Merged phase-2 prep: raw GRU/proj weights -> bf16, biases -> f32.
// Runs AFTER phase 1 (outputs alias the dead Hbst region).
__global__ void prep2(const void* __restrict__ gWih, const void* __restrict__ gWhh,
                      const void* __restrict__ projW, const void* __restrict__ gbih,
                      const void* __restrict__ gbhh, const void* __restrict__ projb,
                      bf16* __restrict__ gWihb, bf16* __restrict__ gWhhb,
                      bf16* __restrict__ projWb, float* __restrict__ gbihf,
                      float* __restrict__ gbhhf, float* __restrict__ projbf,
                      const int* __restrict__ flagp) {
  const int isb = *flagp;
  int i = blockIdx.x * 256 + threadIdx.x;
  if (i < 3072 * C_) { gWihb[i] = __float2bfloat16(ldraw(gWih, i, isb)); return; }
  i -= 3072 * C_;
  if (i < 3072 * C_) { gWhhb[i] = __float2bfloat16(ldraw(gWhh, i, isb)); return; }
  i -= 3072 * C_;
  if (i < C_ * C_) { projWb[i] = __float2bfloat16(ldraw(projW, i, isb)); return; }
  i -= C_ * C_;
  if (i < 3072) { gbihf[i] = ldraw(gbih, i, isb); return; }
  i -= 3072;
  if (i < 3072) { gbhhf[i] = ldraw(gbhh, i, isb); return; }
  i -= 3072;
  if (i < C_) { projbf[i] = ldraw(projb, i, isb); }
}

__global__ void zero_u4(uint4* __restrict__ p, int n16) {
  int i = blockIdx.x * 256 + threadIdx.x;
  if (i < n16) p[i] = make_uint4(0u, 0u, 0u, 0u);
}

// Dense adjacency counts: cnt[d][s] = #edges s->d (int atomics, 65536 total).
__global__ void edge_cnt(const int* __restrict__ ei, int* __restrict__ cnt) {
  int e = blockIdx.x * 256 + threadIdx.x;
  if (e < NE_) {
    int s = ei[e], d = ei[NE_ + e];
    atomicAdd(&cnt[(size_t)d * B_ + s], 1);
  }
}
__global__ void cnt2bf(const int* __restrict__ cnt, bf16* __restrict__ A) {
  int i = blockIdx.x * 256 + threadIdx.x;  // 4M
  A[i] = __float2bfloat16((float)cnt[i]);
}

__global__ void gru_ew(const float* __restrict__ gi, const float* __restrict__ gh,
                       float* __restrict__ h, bf16* __restrict__ hb16) {
  int i = blockIdx.x * 256 + threadIdx.x;
  int b = i >> 10, j = i & 1023;
  const float* gib = gi + (size_t)b * 3072;
  const float* ghb = gh + (size_t)b * 3072;
  float r = sigf(gib[j] + ghb[j]);
  float z = sigf(gib[1024 + j] + ghb[1024 + j]);
  float n = tanhfast(gib[2048 + j] + r * ghb[2048 + j]);
  float hv = (1.f - z) * n + z * h[i];
  h[i] = hv;
  hb16[i] = __float2bfloat16(hv);
}

__global__ void spcvt(const float* __restrict__ Spf, bf16* __restrict__ Sp) {
  int i = blockIdx.x * 256 + threadIdx.x;
  Sp[i] = __float2bfloat16(Spf[i]);
}

__global__ void sentinel(bf16* __restrict__ o, int n, float v) {
  int i = blockIdx.x * 256 + threadIdx.x;
  if (i < n) o[i] = __float2bfloat16(v);
}

extern "C" void kernel_launch(void* const* d_in, const int* in_sizes, int n_in,
                              void* d_out, int out_size, void* d_ws, size_t ws_size,
                              hipStream_t stream) {
  const int* x = (const int*)d_in[0];
  const int* ei = (const int*)d_in[1];
  const void* emb = d_in[2];
  const void* Wih_f = d_in[3];
  const void* Whh_f = d_in[4];
  const void* bih_f = d_in[5];
  const void* bhh_f = d_in[6];
  const void* Wih_b = d_in[7];
  const void* Whh_b = d_in[8];
  const void* bih_b = d_in[9];
  const void* bhh_b = d_in[10];
  const void* label = d_in[11];
  const void* ggcw = d_in[12];
  const void* gWih = d_in[13];
  const void* gWhh = d_in[14];
  const void* gbih = d_in[15];
  const void* gbhh = d_in[16];
  const void* projW = d_in[17];
  const void* projb = d_in[18];
  (void)in_sizes; (void)n_in;

  const size_t NEED = (size_t)112 * 1024 * 1024;
  if (ws_size < NEED) {
    float v = 100.f + (float)(ws_size >> 24);
    sentinel<<<(out_size + 255) / 256, 256, 0, stream>>>((bf16*)d_out, out_size, v);
    return;
  }

  char* w = (char*)d_ws;
  size_t off = 0;
  auto alloc = [&](size_t bytes) {
    char* p = w + off;
    off += (bytes + 255) & ~(size_t)255;
    return p;
  };
  // ---- persistent (~14.6 MB) ----
  int* dflag = (int*)alloc(256);
  bf16* Wcat = (bf16*)alloc((size_t)2 * NP * KC * 2);
  float* bcat = (float*)alloc((size_t)2 * NP * 4);
  bf16* lnp = (bf16*)alloc((size_t)C_ * KC * 2);
  bf16* ggct = (bf16*)alloc((size_t)2 * C_ * C_ * 2);
  bf16* Sp = (bf16*)alloc((size_t)B_ * KC * 2);
  bf16* embtail = (bf16*)alloc((size_t)V_ * 32 * 2);
  const size_t phase_base = off;
  // ---- phase 1 (LSTM): ~94.4 MB (Spf,hpad,cst contiguous for one zero) ----
  float* Spf = (float*)alloc((size_t)B_ * KC * 4);
  bf16* hpad = (bf16*)alloc((size_t)4 * B_ * HP * 2);
  float* cst = (float*)alloc((size_t)2 * B_ * HP * 4);
  bf16* Hfst = (bf16*)alloc((size_t)32 * B_ * H_ * 2);  // hf[t] for t=0..31
  bf16* Hbst = (bf16*)alloc((size_t)32 * B_ * H_ * 2);  // hb[t] for t=32..63
  // ---- phase 2 (graph): ~94.5 MB, aliases phase 1 ----
  off = phase_base;
  float* hbuf = (float*)alloc((size_t)B_ * C_ * 4);
  bf16* hb16 = (bf16*)alloc((size_t)B_ * C_ * 2);
  bf16* m1t = (bf16*)alloc((size_t)C_ * B_ * 2);     // m transposed [c][s]
  bf16* aggb = (bf16*)alloc((size_t)B_ * C_ * 2);
  bf16* Acnt = (bf16*)alloc((size_t)B_ * B_ * 2);    // dense adjacency counts
  float* gi = (float*)alloc((size_t)B_ * 3072 * 4);  // cnt(i32, 16MB) aliases head of gi
  float* gh = (float*)alloc((size_t)B_ * 3072 * 4);
  bf16* gWihb = (bf16*)alloc((size_t)3072 * C_ * 2);  // pre-converted bf16 weights
  bf16* gWhhb = (bf16*)alloc((size_t)3072 * C_ * 2);
  bf16* projWb = (bf16*)alloc((size_t)C_ * C_ * 2);
  float* gbihf = (float*)alloc(3072 * 4);
  float* gbhhf = (float*)alloc(3072 * 4);
  float* projbf = (float*)alloc(C_ * 4);
  int* cnt = (int*)gi;

  // ---- dtype detection + merged prep ----
  detect_dtype<<<1, 256, 0, stream>>>((const unsigned short*)emb, dflag);
  prep_all<<<1024 + (2 * NP * KC + 2 * C_ * C_ + V_ * 32) / 256, 256, 0, stream>>>(
      Wih_f, Whh_f, bih_f, bhh_f, Wih_b, Whh_b, bih_b, bhh_b, label, ggcw, emb,
      Wcat, bcat, lnp, ggct, embtail, dflag);
  // one zero over contiguous Spf+hpad+cst (3 x 5,242,880 B, 256-aligned)
  zero_u4<<<(3 * 327680) / 256, 256, 0, stream>>>((uint4*)Spf, 3 * 327680);

  // ---- phase 1: fused bidir LSTM, 64 sequential dispatches ----
  for (int s = 0; s < T_; ++s)
    lstm_step<<<dim3(NP / 128, B_ / 64, 3), 256, 0, stream>>>(emb, embtail, x, Wcat, bcat,
                                                              hpad, cst, Hfst, Hbst, Spf,
                                                              s, dflag);
  normacc_fin<<<B_ / 4, 256, 0, stream>>>(hpad, Hfst, Hbst, Spf);
  spcvt<<<(B_ * KC) / 256, 256, 0, stream>>>(Spf, Sp);

  // ---- phase 2 prep (after phase 1: outputs alias dead Hbst region) ----
  prep2<<<(2 * 3072 * C_ + C_ * C_ + 2 * 3072 + C_) / 256, 256, 0, stream>>>(
      gWih, gWhh, projW, gbih, gbhh, projb, gWihb, gWhhb, projWb, gbihf, gbhhf, projbf, dflag);

  // ---- phase 2: label scores + GatedGraphConv (dense-adjacency GEMM) + proj ----
  gemm_bt<<<dim3(C_ / 128, B_ / 128), 256, 0, stream>>>(Sp, KC, lnp, KC, nullptr,
                                                        hbuf, hb16, C_, KC, nullptr, 0,
                                                        nullptr, nullptr, nullptr, nullptr);
  // adjacency counts (built once, reused by both layers)
  zero_u4<<<(B_ * B_ * 4 / 16) / 256, 256, 0, stream>>>((uint4*)cnt, B_ * B_ * 4 / 16);
  edge_cnt<<<NE_ / 256, 256, 0, stream>>>(ei, cnt);
  cnt2bf<<<(B_ * B_) / 256, 256, 0, stream>>>(cnt, Acnt);
  for (int l = 0; l < 2; ++l) {
    // m1t[c][s] = sum_k ggcw[l][k][c] * h[s][k]   (A/W roles swapped)
    gemm_bt<<<dim3(B_ / 128, C_ / 128), 256, 0, stream>>>(ggct + (size_t)l * C_ * C_, C_,
                                                          hb16, C_, nullptr,
                                                          nullptr, m1t, B_, C_, nullptr, 0,
                                                          nullptr, nullptr, nullptr, nullptr);
    // agg[d][c] = sum_s Acnt[d][s] * m1t[c][s]
    gemm_bt<<<dim3(C_ / 128, B_ / 128), 256, 0, stream>>>(Acnt, B_, m1t, B_, nullptr,
                                                          nullptr, aggb, C_, B_, nullptr, 0,
                                                          nullptr, nullptr, nullptr, nullptr);
    // gi and gh batched into one dispatch (z=0: gi, z=1: gh)
    gemm_bt<<<dim3(3072 / 128, B_ / 128, 2), 256, 0, stream>>>(aggb, C_, gWihb, C_, gbihf,
                                                               gi, nullptr, 3072, C_, nullptr, 0,
                                                               hb16, gWhhb, gbhhf, gh);
    gru_ew<<<(B_ * C_) / 256, 256, 0, stream>>>(gi, gh, hbuf, hb16);
  }
  gemm_bt<<<dim3(C_ / 128, B_ / 128), 256, 0, stream>>>(hb16, C_, projWb, C_, projbf,
                                                        (float*)d_out, (bf16*)d_out, C_, C_,
                                                        dflag, 1,
                                                        nullptr, nullptr, nullptr, nullptr);
}

// Round 8
// 2225.740 us; speedup vs baseline: 2.1789x; 1.0205x over previous
//
#include <hip/hip_runtime.h>
#include <hip/hip_bf16.h>
#include <stdint.h>

typedef __hip_bfloat16 bf16;
typedef __attribute__((ext_vector_type(8))) short frag16;
typedef __attribute__((ext_vector_type(4))) float f32x4;

#define B_ 2048
#define T_ 64
#define E_ 300
#define H_ 300
#define C_ 1024
#define V_ 50000
#define NE_ 65536
#define HP 320     // padded E/H half of concat-K
#define KC 640     // padded concat K (320 x + 320 h)
#define NP 1280    // padded 4H, gate-interleaved n = 4*j + q

static __device__ __forceinline__ float sigf(float x) {
  x = fminf(fmaxf(x, -30.f), 30.f);
  return 1.f / (1.f + __expf(-x));
}
static __device__ __forceinline__ float tanhfast(float x) {
  x = fminf(fmaxf(x, -15.f), 15.f);
  float e = __expf(2.f * x);
  return (e - 1.f) / (e + 1.f);
}
static __device__ __forceinline__ float ldraw(const void* p, size_t i, int isb) {
  return isb ? __bfloat162float(((const bf16*)p)[i]) : ((const float*)p)[i];
}
static __device__ __forceinline__ short b2s(bf16 b) {
  short s; __builtin_memcpy(&s, &b, 2); return s;
}
static __device__ __forceinline__ short4 f4tob4(float4 v) {
  return make_short4(b2s(__float2bfloat16(v.x)), b2s(__float2bfloat16(v.y)),
                     b2s(__float2bfloat16(v.z)), b2s(__float2bfloat16(v.w)));
}

// Direct global->LDS 16B per lane. LDS dest wave-uniform; lane i lands at
// base + i*16B. Global source per-lane.
static __device__ __forceinline__ void g2l16(const void* g, void* l) {
  __builtin_amdgcn_global_load_lds(
      (const __attribute__((address_space(1))) void*)(uintptr_t)g,
      (__attribute__((address_space(3))) void*)(uintptr_t)l, 16, 0, 0);
}

// Input dtype detector: bit14 of low half-word is 0 in bf16 world (|v|<2),
// ~Bernoulli(0.5) in f32 world (mantissa bits).
__global__ void detect_dtype(const unsigned short* __restrict__ e2, int* __restrict__ flag) {
  __shared__ int red[4];
  int tid = threadIdx.x;
  int ones = 0;
#pragma unroll
  for (int s = 0; s < 16; ++s) ones += (e2[2 * (tid * 16 + s)] >> 14) & 1;
  for (int off = 32; off > 0; off >>= 1) ones += __shfl_down(ones, off, 64);
  if ((tid & 63) == 0) red[tid >> 6] = ones;
  __syncthreads();
  if (tid == 0) {
    int tot = red[0] + red[1] + red[2] + red[3];
    *flag = (tot < 1024) ? 1 : 0;  // 1 = bf16 inputs, 0 = f32 inputs
  }
}

// C[m][n] = sum_k A[m][k]*W[n][k] (+bias[n]); M,N mult of 128, K of 32.
// A,W bf16, bias f32. Double-buffered global_load_lds with COUNTED vmcnt
// (T4): tile k+1's 4 loads/wave stay in flight across both barriers; only
// the last tile drains to 0. gridDim.z==2: z==1 uses (A2,W2,bias2,Cf2).
// outmode=1: d_out in raw dtype per *rawp.
__global__ __launch_bounds__(256) void gemm_bt(
    const bf16* A, int lda, const bf16* W, int ldw, const float* bias,
    float* Cf, bf16* Cb, int ldc, int K,
    const int* __restrict__ rawp, int outmode,
    const bf16* A2, const bf16* W2, const float* bias2, float* Cf2) {
  if (blockIdx.z) { A = A2; W = W2; bias = bias2; Cf = Cf2; Cb = nullptr; }
  __shared__ __align__(16) short As[2][128 * 32];
  __shared__ __align__(16) short Bs[2][128 * 32];
  const int isb = rawp ? *rawp : 1;  // output dtype only
  const int n0 = blockIdx.x * 128, m0 = blockIdx.y * 128;
  const int lane = threadIdx.x & 63, wv = threadIdx.x >> 6;
  const int wm = (wv & 1) * 64, wn = (wv >> 1) * 64;
  // gload geometry: wave wv covers 32 rows (2 calls x 16); lane -> (row,chunk)
  const int gr = lane >> 2;          // row within 16-row call group
  const int gc = (lane & 3) * 8;     // short col within 32-k tile
  const short* pA0 = (const short*)A + (size_t)(m0 + wv * 32 + gr) * lda + gc;
  const short* pA1 = pA0 + (size_t)16 * lda;
  const short* pB0 = (const short*)W + (size_t)(n0 + wv * 32 + gr) * ldw + gc;
  const short* pB1 = pB0 + (size_t)16 * ldw;

  auto issueT = [&](int k0, int buf) {  // 4 VMEM ops per wave
    short* a = &As[buf][wv * 1024];
    short* b = &Bs[buf][wv * 1024];
    g2l16(pA0 + k0, a);
    g2l16(pA1 + k0, a + 512);
    g2l16(pB0 + k0, b);
    g2l16(pB1 + k0, b + 512);
  };

  f32x4 acc[4][4];
#pragma unroll
  for (int i = 0; i < 4; ++i)
#pragma unroll
    for (int j = 0; j < 4; ++j) acc[i][j] = (f32x4){0.f, 0.f, 0.f, 0.f};

  const int nk = K / 32;
  const int krd = (lane >> 4) * 8;
  const int rsel = lane & 15;
  issueT(0, 0);
  if (nk > 1) issueT(32, 1);
  for (int kk = 0; kk < nk; ++kk) {
    const int cur = kk & 1;
    if (kk + 1 < nk) asm volatile("s_waitcnt vmcnt(4)" ::: "memory");
    else asm volatile("s_waitcnt vmcnt(0)" ::: "memory");
    __builtin_amdgcn_s_barrier();
    frag16 af[4], bfg[4];
#pragma unroll
    for (int i = 0; i < 4; ++i) af[i] = *(const frag16*)&As[cur][(wm + i * 16 + rsel) * 32 + krd];
#pragma unroll
    for (int i = 0; i < 4; ++i) bfg[i] = *(const frag16*)&Bs[cur][(wn + i * 16 + rsel) * 32 + krd];
#pragma unroll
    for (int i = 0; i < 4; ++i)
#pragma unroll
      for (int j = 0; j < 4; ++j)
        acc[i][j] = __builtin_amdgcn_mfma_f32_16x16x32_bf16(af[i], bfg[j], acc[i][j], 0, 0, 0);
    asm volatile("" ::: "memory");
    __builtin_amdgcn_s_barrier();  // all waves done reading buf cur
    if (kk + 2 < nk) issueT(32 * (kk + 2), cur);
  }
  const int rq = (lane >> 4) * 4, cq = lane & 15;
#pragma unroll
  for (int j = 0; j < 4; ++j) {
    int cidx = n0 + wn + j * 16 + cq;
    float bv = bias ? bias[cidx] : 0.f;
#pragma unroll
    for (int i = 0; i < 4; ++i) {
      int rbase = m0 + wm + i * 16 + rq;
#pragma unroll
      for (int r = 0; r < 4; ++r) {
        float v = acc[i][j][r] + bv;
        size_t idx = (size_t)(rbase + r) * ldc + cidx;
        if (outmode) {
          if (isb) Cb[idx] = __float2bfloat16(v);
          else Cf[idx] = v;
        } else {
          if (Cf) Cf[idx] = v;
          if (Cb) Cb[idx] = __float2bfloat16(v);
        }
      }
    }
  }
}

// Two-pair norm-accumulate: Spf[b] += concat(hfA,hbA)/||.|| + concat(hfB,hbB)/||.||
// One wave per b (both pairs in one wave -> no RMW race on Spf[b]).
static __device__ __forceinline__ void normacc_row2(
    const bf16* hfA, const bf16* hbA, const bf16* hfB, const bf16* hbB,
    float* __restrict__ Spf, int b, int lane) {
  float vA[10], vB[10];
  float sA = 0.f, sB = 0.f;
#pragma unroll
  for (int s = 0; s < 10; ++s) {
    int d = lane + 64 * s;
    float a = 0.f, c = 0.f;
    if (d < 300) {
      a = __bfloat162float(hfA[d]);
      c = __bfloat162float(hfB[d]);
    } else if (d < 600) {
      a = __bfloat162float(hbA[d - 300]);
      c = __bfloat162float(hbB[d - 300]);
    }
    vA[s] = a; vB[s] = c;
    sA += a * a; sB += c * c;
  }
#pragma unroll
  for (int off = 32; off > 0; off >>= 1) {
    sA += __shfl_xor(sA, off, 64);
    sB += __shfl_xor(sB, off, 64);
  }
  float kA = 1.f / fmaxf(sqrtf(sA), 1e-8f);
  float kB = 1.f / fmaxf(sqrtf(sB), 1e-8f);
  float* dst = Spf + (size_t)b * KC;
#pragma unroll
  for (int s = 0; s < 10; ++s) {
    int d = lane + 64 * s;
    if (d < 600) dst[d] += vA[s] * kA + vB[s] * kB;
  }
}

// Fused bidirectional LSTM timestep. z=0: fwd GEMM (tt=s). z=1: bwd GEMM
// (tt=63-s). z=2: paired normacc (s>=33). fwd stores hf[t<32] in Hfst,
// bwd hb[t>=32] in Hbst. GEMM tile 128(N)x64(M). isb path: double-buffered
// global_load_lds with counted vmcnt(3) (T4); f32-emb path: R6 single-buffer
// __syncthreads fallback. (Named LDS pointers + ternary select — pointer
// arrays of LDS addrs trip a gfx950 static-initializer addrspacecast bug.)
__global__ __launch_bounds__(256) void lstm_step(
    const void* __restrict__ emb, const bf16* __restrict__ embtail,
    const int* __restrict__ x,
    const bf16* __restrict__ Wcat, const float* __restrict__ bcat,
    bf16* __restrict__ hpad, float* __restrict__ cstate,
    bf16* __restrict__ Hfst, bf16* __restrict__ Hbst, float* __restrict__ Spf,
    int s, const int* __restrict__ flagp) {
  const int pb = s & 1;
  const int lane = threadIdx.x & 63, wv = threadIdx.x >> 6;

  if (blockIdx.z == 2) {  // paired normacc plane (320 blocks)
    if (s >= 33) {
      int bid = blockIdx.x + gridDim.x * blockIdx.y;  // 0..319
      const bf16* hinf = hpad + (size_t)pb * B_ * HP;        // hf[s-1]
      const bf16* hinb = hpad + (size_t)(2 + pb) * B_ * HP;  // hb[64-s]
      const int t1 = s - 1, t2 = 64 - s;
#pragma unroll
      for (int rep = 0; rep < 2; ++rep) {
        int b = bid * 4 + wv + 1280 * rep;
        if (b < B_)
          normacc_row2(hinf + (size_t)b * HP,
                       Hbst + ((size_t)(t1 - 32) * B_ + b) * H_,
                       Hfst + ((size_t)t2 * B_ + b) * H_,
                       hinb + (size_t)b * HP, Spf, b, lane);
      }
    }
    return;
  }

  __shared__ __align__(16) char smem[24576];
  short* As0 = (short*)smem;              // 64x32 = 4 KB
  short* As1 = (short*)(smem + 4096);
  short* Bs0 = (short*)(smem + 8192);     // 128x32 = 8 KB
  short* Bs1 = (short*)(smem + 16384);
  float* epi = (float*)smem;  // reused: 64x64 fp32 = 16 KB

  const int dir = blockIdx.z;
  const int tt = dir ? (T_ - 1 - s) : s;
  const int isb = *flagp;
  const bf16* hin = hpad + (size_t)(dir * 2 + pb) * B_ * HP;
  const bf16* Wd = Wcat + (size_t)dir * NP * KC;
  bf16* hout = hpad + (size_t)(dir * 2 + (1 - pb)) * B_ * HP;
  float* cs = cstate + (size_t)dir * B_ * HP;
  const int n0 = blockIdx.x * 128, m0 = blockIdx.y * 64;
  const int wm = (wv & 1) * 32, wn = (wv >> 1) * 64;
  // gload geometry
  const int gr = lane >> 2;        // row within 16-row call group
  const int gc = (lane & 3) * 8;   // short col within 32-k tile
  const int arow = m0 + wv * 16 + gr;            // A row owned by this lane
  const int tok = x[arow * T_ + tt];             // emb token for this row
  const short* es = (const short*)emb;
  const float* ef = (const float*)emb;
  const short* px = es + (size_t)tok * E_ + gc;              // bf16 emb row
  const short* ptail = (const short*)embtail + (size_t)tok * 32 + gc;
  const short* ph = (const short*)hin + (size_t)arow * HP + gc;
  const short* pB0 = (const short*)Wd + (size_t)(n0 + wv * 32 + gr) * KC + gc;
  const short* pB1 = pB0 + (size_t)16 * KC;

  auto issueT = [&](int k0, int buf) {  // 3 VMEM ops per wave
    short* a = (buf ? As1 : As0) + wv * 512;
    short* b = (buf ? Bs1 : Bs0) + wv * 1024;
    if (k0 < HP) {
      // chunks never straddle E_ for k0<288 (max end 256+24+8=288);
      // k0==288 reads the prepadded tail table (cols 288..319).
      g2l16(k0 == 288 ? ptail : (px + k0), a);
    } else {
      g2l16(ph + (k0 - HP), a);  // hpad cols 300..319 are persistent zeros
    }
    g2l16(pB0 + k0, b);
    g2l16(pB1 + k0, b + 512);
  };

  f32x4 acc[2][4];
#pragma unroll
  for (int i = 0; i < 2; ++i)
#pragma unroll
    for (int j = 0; j < 4; ++j) acc[i][j] = (f32x4){0.f, 0.f, 0.f, 0.f};

  const int rsel = lane & 15, krd = (lane >> 4) * 8;
  const int NKT = KC / 32;  // 20

  auto mfma8 = [&](const short* Ap, const short* Bp) {
    frag16 af[2], bfg[4];
#pragma unroll
    for (int i = 0; i < 2; ++i) af[i] = *(const frag16*)&Ap[(wm + i * 16 + rsel) * 32 + krd];
#pragma unroll
    for (int j = 0; j < 4; ++j) bfg[j] = *(const frag16*)&Bp[(wn + j * 16 + rsel) * 32 + krd];
#pragma unroll
    for (int i = 0; i < 2; ++i)
#pragma unroll
      for (int j = 0; j < 4; ++j)
        acc[i][j] = __builtin_amdgcn_mfma_f32_16x16x32_bf16(af[i], bfg[j], acc[i][j], 0, 0, 0);
  };

  if (isb) {
    // counted-vmcnt double-buffer pipeline
    issueT(0, 0);
    issueT(32, 1);
    for (int kk = 0; kk < NKT; ++kk) {
      const int cur = kk & 1;
      if (kk + 1 < NKT) asm volatile("s_waitcnt vmcnt(3)" ::: "memory");
      else asm volatile("s_waitcnt vmcnt(0)" ::: "memory");
      __builtin_amdgcn_s_barrier();
      mfma8(cur ? As1 : As0, cur ? Bs1 : Bs0);
      asm volatile("" ::: "memory");
      __builtin_amdgcn_s_barrier();  // all waves done reading buf cur
      if (kk + 2 < NKT) issueT(32 * (kk + 2), cur);
    }
  } else {
    // f32-emb fallback: single buffer, reg-staged x-half, full barriers
    for (int kk = 0; kk < NKT; ++kk) {
      const int k0 = kk * 32;
      if (k0 < HP) {
        int c0 = k0 + gc;
        float4 fa = (c0 < E_) ? *(const float4*)(ef + (size_t)tok * E_ + c0)
                              : make_float4(0.f, 0.f, 0.f, 0.f);
        float4 fb = (c0 + 4 < E_) ? *(const float4*)(ef + (size_t)tok * E_ + c0 + 4)
                                  : make_float4(0.f, 0.f, 0.f, 0.f);
        short* d = As0 + (wv * 16 + gr) * 32 + gc;
        *(short4*)d = f4tob4(fa);
        *(short4*)(d + 4) = f4tob4(fb);
      } else {
        g2l16(ph + (k0 - HP), As0 + wv * 512);
      }
      g2l16(pB0 + k0, Bs0 + wv * 1024);
      g2l16(pB1 + k0, Bs0 + wv * 1024 + 512);
      __syncthreads();
      mfma8(As0, Bs0);
      __syncthreads();
    }
  }

  const int rq = (lane >> 4) * 4, cq = lane & 15;
#pragma unroll
  for (int p = 0; p < 2; ++p) {
    if (wn == p * 64) {
#pragma unroll
      for (int j = 0; j < 4; ++j) {
        int cl = j * 16 + cq;
        float bv = bcat[dir * NP + n0 + p * 64 + cl];
#pragma unroll
        for (int i = 0; i < 2; ++i) {
          int rl = wm + i * 16 + rq;
#pragma unroll
          for (int r = 0; r < 4; ++r) epi[(rl + r) * 64 + cl] = acc[i][j][r] + bv;
        }
      }
    }
    __syncthreads();
    int jbase = (n0 + p * 64) >> 2;
    for (int it = threadIdx.x; it < 64 * 16; it += 256) {
      int rl = it >> 4, jl = it & 15;
      int jg = jbase + jl;
      if (jg < H_) {
        const float* row = epi + rl * 64 + jl * 4;
        float iv = sigf(row[0]);
        float fv = sigf(row[1]);
        float gv = tanhfast(row[2]);
        float ov = sigf(row[3]);
        int b = m0 + rl;
        float c = fv * cs[(size_t)b * HP + jg] + iv * gv;
        float h = ov * tanhfast(c);
        cs[(size_t)b * HP + jg] = c;
        bf16 hb = __float2bfloat16(h);
        hout[(size_t)b * HP + jg] = hb;
        if (dir) {
          if (tt >= 32) Hbst[((size_t)(tt - 32) * B_ + b) * H_ + jg] = hb;
        } else if (tt < 32) {
          Hfst[((size_t)tt * B_ + b) * H_ + jg] = hb;
        }
      }
    }
    __syncthreads();
  }
}

// Cleanup pairs t=63 (hf: fwd hout plane 0, hb: Hbst[31]) and t=0
// (hf: Hfst[0], hb: bwd hout plane 2) after the fused loop.
__global__ __launch_bounds__(256) void normacc_fin(const bf16* __restrict__ hpad,
                                                   const bf16* __restrict__ Hfst,
                                                   const bf16* __restrict__ Hbst,
                                                   float* __restrict__ Spf) {
  int b = blockIdx.x * 4 + (threadIdx.x >> 6);
  int lane = threadIdx.x & 63;
  normacc_row2(hpad + (size_t)b * HP,
               Hbst + ((size_t)31 * B_ + b) * H_,
               Hfst + (size_t)b * H_,
               hpad + (size_t)2 * B_ * HP + (size_t)b * HP, Spf, b, lane);
}

// Merged prep: blocks [0,1024) = labelnorm; blocks >=1024 = elementwise
// {prep_wcat | transpose_ggc | embtail} by index range.
__global__ void prep_all(const void* __restrict__ Wih_f, const void* __restrict__ Whh_f,
                         const void* __restrict__ bih_f, const void* __restrict__ bhh_f,
                         const void* __restrict__ Wih_b, const void* __restrict__ Whh_b,
                         const void* __restrict__ bih_b, const void* __restrict__ bhh_b,
                         const void* __restrict__ label, const void* __restrict__ ggcw,
                         const void* __restrict__ emb,
                         bf16* __restrict__ Wcat, float* __restrict__ bcat,
                         bf16* __restrict__ lnp, bf16* __restrict__ ggct,
                         bf16* __restrict__ embtail,
                         const int* __restrict__ flagp) {
  const int isb = *flagp;
  if (blockIdx.x < 1024) {  // labelnorm, l = blockIdx.x
    int l = blockIdx.x, tid = threadIdx.x;
    __shared__ float red[4];
    float v[3];
    float ss = 0.f;
#pragma unroll
    for (int s = 0; s < 3; ++s) {
      int d = tid + 256 * s;
      v[s] = (d < 600) ? ldraw(label, (size_t)l * 600 + d, isb) : 0.f;
      ss += v[s] * v[s];
    }
    for (int off = 32; off > 0; off >>= 1) ss += __shfl_down(ss, off, 64);
    if ((tid & 63) == 0) red[tid >> 6] = ss;
    __syncthreads();
    float scale = 1.f / fmaxf(sqrtf(red[0] + red[1] + red[2] + red[3]), 1e-8f);
#pragma unroll
    for (int s = 0; s < 3; ++s) {
      int d = tid + 256 * s;
      if (d < KC) lnp[(size_t)l * KC + d] = __float2bfloat16(v[s] * scale);
    }
    return;
  }
  int i = (blockIdx.x - 1024) * 256 + threadIdx.x;
  if (i < 2 * NP * KC) {  // prep_wcat
    int k = i % KC;
    int n = (i / KC) % NP;
    int dir = i / (KC * NP);
    int j = n >> 2, q = n & 3;
    const void* Wih = dir ? Wih_b : Wih_f;
    const void* Whh = dir ? Whh_b : Whh_f;
    float v = 0.f;
    if (j < H_) {
      int row = q * H_ + j;
      if (k < E_) v = ldraw(Wih, (size_t)row * E_ + k, isb);
      else if (k >= HP && k < HP + H_) v = ldraw(Whh, (size_t)row * H_ + (k - HP), isb);
    }
    Wcat[i] = __float2bfloat16(v);
    if (k == 0) {
      const void* bih = dir ? bih_b : bih_f;
      const void* bhh = dir ? bhh_b : bhh_f;
      bcat[dir * NP + n] =
          (j < H_) ? (ldraw(bih, q * H_ + j, isb) + ldraw(bhh, q * H_ + j, isb)) : 0.f;
    }
    return;
  }
  i -= 2 * NP * KC;
  if (i < 2 * C_ * C_) {  // transpose_ggc: Wt[l][n][k] = ggc[l][k][n]
    int k = i & 1023, n = (i >> 10) & 1023, l = i >> 20;
    size_t src = ((size_t)l << 20) | ((size_t)k << 10) | (size_t)n;
    ggct[i] = __float2bfloat16(ldraw(ggcw, src, isb));
    return;
  }
  i -= 2 * C_ * C_;
  if (i < V_ * 32) {  // embtail[v][c] = (c<12) ? emb[v][288+c] : 0
    int v = i >> 5, c = i & 31;
    float val = (c < E_ - 288) ? ldraw(emb, (size_t)v * E_ + 288 + c, isb) : 0.f;
    embtail[i] = __float2bfloat16(val);
  }
}

// Merged phase-2 prep: raw GRU/proj weights -> bf16, biases -> f32.
// Runs AFTER phase 1 (outputs alias the dead Hbst region).
__global__ void prep2(const void* __restrict__ gWih, const void* __restrict__ gWhh,
                      const void* __restrict__ projW, const void* __restrict__ gbih,
                      const void* __restrict__ gbhh, const void* __restrict__ projb,
                      bf16* __restrict__ gWihb, bf16* __restrict__ gWhhb,
                      bf16* __restrict__ projWb, float* __restrict__ gbihf,
                      float* __restrict__ gbhhf, float* __restrict__ projbf,
                      const int* __restrict__ flagp) {
  const int isb = *flagp;
  int i = blockIdx.x * 256 + threadIdx.x;
  if (i < 3072 * C_) { gWihb[i] = __float2bfloat16(ldraw(gWih, i, isb)); return; }
  i -= 3072 * C_;
  if (i < 3072 * C_) { gWhhb[i] = __float2bfloat16(ldraw(gWhh, i, isb)); return; }
  i -= 3072 * C_;
  if (i < C_ * C_) { projWb[i] = __float2bfloat16(ldraw(projW, i, isb)); return; }
  i -= C_ * C_;
  if (i < 3072) { gbihf[i] = ldraw(gbih, i, isb); return; }
  i -= 3072;
  if (i < 3072) { gbhhf[i] = ldraw(gbhh, i, isb); return; }
  i -= 3072;
  if (i < C_) { projbf[i] = ldraw(projb, i, isb); }
}

__global__ void zero_u4(uint4* __restrict__ p, int n16) {
  int i = blockIdx.x * 256 + threadIdx.x;
  if (i < n16) p[i] = make_uint4(0u, 0u, 0u, 0u);
}

// Dense adjacency counts: cnt[d][s] = #edges s->d (int atomics, 65536 total).
__global__ void edge_cnt(const int* __restrict__ ei, int* __restrict__ cnt) {
  int e = blockIdx.x * 256 + threadIdx.x;
  if (e < NE_) {
    int s = ei[e], d = ei[NE_ + e];
    atomicAdd(&cnt[(size_t)d * B_ + s], 1);
  }
}
__global__ void cnt2bf(const int* __restrict__ cnt, bf16* __restrict__ A) {
  int i = blockIdx.x * 256 + threadIdx.x;  // 4M
  A[i] = __float2bfloat16((float)cnt[i]);
}

__global__ void gru_ew(const float* __restrict__ gi, const float* __restrict__ gh,
                       float* __restrict__ h, bf16* __restrict__ hb16) {
  int i = blockIdx.x * 256 + threadIdx.x;
  int b = i >> 10, j = i & 1023;
  const float* gib = gi + (size_t)b * 3072;
  const float* ghb = gh + (size_t)b * 3072;
  float r = sigf(gib[j] + ghb[j]);
  float z = sigf(gib[1024 + j] + ghb[1024 + j]);
  float n = tanhfast(gib[2048 + j] + r * ghb[2048 + j]);
  float hv = (1.f - z) * n + z * h[i];
  h[i] = hv;
  hb16[i] = __float2bfloat16(hv);
}

__global__ void spcvt(const float* __restrict__ Spf, bf16* __restrict__ Sp) {
  int i = blockIdx.x * 256 + threadIdx.x;
  Sp[i] = __float2bfloat16(Spf[i]);
}

__global__ void sentinel(bf16* __restrict__ o, int n, float v) {
  int i = blockIdx.x * 256 + threadIdx.x;
  if (i < n) o[i] = __float2bfloat16(v);
}

extern "C" void kernel_launch(void* const* d_in, const int* in_sizes, int n_in,
                              void* d_out, int out_size, void* d_ws, size_t ws_size,
                              hipStream_t stream) {
  const int* x = (const int*)d_in[0];
  const int* ei = (const int*)d_in[1];
  const void* emb = d_in[2];
  const void* Wih_f = d_in[3];
  const void* Whh_f = d_in[4];
  const void* bih_f = d_in[5];
  const void* bhh_f = d_in[6];
  const void* Wih_b = d_in[7];
  const void* Whh_b = d_in[8];
  const void* bih_b = d_in[9];
  const void* bhh_b = d_in[10];
  const void* label = d_in[11];
  const void* ggcw = d_in[12];
  const void* gWih = d_in[13];
  const void* gWhh = d_in[14];
  const void* gbih = d_in[15];
  const void* gbhh = d_in[16];
  const void* projW = d_in[17];
  const void* projb = d_in[18];
  (void)in_sizes; (void)n_in;

  const size_t NEED = (size_t)112 * 1024 * 1024;
  if (ws_size < NEED) {
    float v = 100.f + (float)(ws_size >> 24);
    sentinel<<<(out_size + 255) / 256, 256, 0, stream>>>((bf16*)d_out, out_size, v);
    return;
  }

  char* w = (char*)d_ws;
  size_t off = 0;
  auto alloc = [&](size_t bytes) {
    char* p = w + off;
    off += (bytes + 255) & ~(size_t)255;
    return p;
  };
  // ---- persistent (~14.6 MB) ----
  int* dflag = (int*)alloc(256);
  bf16* Wcat = (bf16*)alloc((size_t)2 * NP * KC * 2);
  float* bcat = (float*)alloc((size_t)2 * NP * 4);
  bf16* lnp = (bf16*)alloc((size_t)C_ * KC * 2);
  bf16* ggct = (bf16*)alloc((size_t)2 * C_ * C_ * 2);
  bf16* Sp = (bf16*)alloc((size_t)B_ * KC * 2);
  bf16* embtail = (bf16*)alloc((size_t)V_ * 32 * 2);
  const size_t phase_base = off;
  // ---- phase 1 (LSTM): ~94.4 MB (Spf,hpad,cst contiguous for one zero) ----
  float* Spf = (float*)alloc((size_t)B_ * KC * 4);
  bf16* hpad = (bf16*)alloc((size_t)4 * B_ * HP * 2);
  float* cst = (float*)alloc((size_t)2 * B_ * HP * 4);
  bf16* Hfst = (bf16*)alloc((size_t)32 * B_ * H_ * 2);  // hf[t] for t=0..31
  bf16* Hbst = (bf16*)alloc((size_t)32 * B_ * H_ * 2);  // hb[t] for t=32..63
  // ---- phase 2 (graph): ~94.5 MB, aliases phase 1 ----
  off = phase_base;
  float* hbuf = (float*)alloc((size_t)B_ * C_ * 4);
  bf16* hb16 = (bf16*)alloc((size_t)B_ * C_ * 2);
  bf16* m1t = (bf16*)alloc((size_t)C_ * B_ * 2);     // m transposed [c][s]
  bf16* aggb = (bf16*)alloc((size_t)B_ * C_ * 2);
  bf16* Acnt = (bf16*)alloc((size_t)B_ * B_ * 2);    // dense adjacency counts
  float* gi = (float*)alloc((size_t)B_ * 3072 * 4);  // cnt(i32, 16MB) aliases head of gi
  float* gh = (float*)alloc((size_t)B_ * 3072 * 4);
  bf16* gWihb = (bf16*)alloc((size_t)3072 * C_ * 2);  // pre-converted bf16 weights
  bf16* gWhhb = (bf16*)alloc((size_t)3072 * C_ * 2);
  bf16* projWb = (bf16*)alloc((size_t)C_ * C_ * 2);
  float* gbihf = (float*)alloc(3072 * 4);
  float* gbhhf = (float*)alloc(3072 * 4);
  float* projbf = (float*)alloc(C_ * 4);
  int* cnt = (int*)gi;

  // ---- dtype detection + merged prep ----
  detect_dtype<<<1, 256, 0, stream>>>((const unsigned short*)emb, dflag);
  prep_all<<<1024 + (2 * NP * KC + 2 * C_ * C_ + V_ * 32) / 256, 256, 0, stream>>>(
      Wih_f, Whh_f, bih_f, bhh_f, Wih_b, Whh_b, bih_b, bhh_b, label, ggcw, emb,
      Wcat, bcat, lnp, ggct, embtail, dflag);
  // one zero over contiguous Spf+hpad+cst (3 x 5,242,880 B, 256-aligned)
  zero_u4<<<(3 * 327680) / 256, 256, 0, stream>>>((uint4*)Spf, 3 * 327680);

  // ---- phase 1: fused bidir LSTM, 64 sequential dispatches ----
  for (int s = 0; s < T_; ++s)
    lstm_step<<<dim3(NP / 128, B_ / 64, 3), 256, 0, stream>>>(emb, embtail, x, Wcat, bcat,
                                                              hpad, cst, Hfst, Hbst, Spf,
                                                              s, dflag);
  normacc_fin<<<B_ / 4, 256, 0, stream>>>(hpad, Hfst, Hbst, Spf);
  spcvt<<<(B_ * KC) / 256, 256, 0, stream>>>(Spf, Sp);

  // ---- phase 2 prep (after phase 1: outputs alias dead Hbst region) ----
  prep2<<<(2 * 3072 * C_ + C_ * C_ + 2 * 3072 + C_) / 256, 256, 0, stream>>>(
      gWih, gWhh, projW, gbih, gbhh, projb, gWihb, gWhhb, projWb, gbihf, gbhhf, projbf, dflag);

  // ---- phase 2: label scores + GatedGraphConv (dense-adjacency GEMM) + proj ----
  gemm_bt<<<dim3(C_ / 128, B_ / 128), 256, 0, stream>>>(Sp, KC, lnp, KC, nullptr,
                                                        hbuf, hb16, C_, KC, nullptr, 0,
                                                        nullptr, nullptr, nullptr, nullptr);
  // adjacency counts (built once, reused by both layers)
  zero_u4<<<(B_ * B_ * 4 / 16) / 256, 256, 0, stream>>>((uint4*)cnt, B_ * B_ * 4 / 16);
  edge_cnt<<<NE_ / 256, 256, 0, stream>>>(ei, cnt);
  cnt2bf<<<(B_ * B_) / 256, 256, 0, stream>>>(cnt, Acnt);
  for (int l = 0; l < 2; ++l) {
    // m1t[c][s] = sum_k ggcw[l][k][c] * h[s][k]   (A/W roles swapped)
    gemm_bt<<<dim3(B_ / 128, C_ / 128), 256, 0, stream>>>(ggct + (size_t)l * C_ * C_, C_,
                                                          hb16, C_, nullptr,
                                                          nullptr, m1t, B_, C_, nullptr, 0,
                                                          nullptr, nullptr, nullptr, nullptr);
    // agg[d][c] = sum_s Acnt[d][s] * m1t[c][s]
    gemm_bt<<<dim3(C_ / 128, B_ / 128), 256, 0, stream>>>(Acnt, B_, m1t, B_, nullptr,
                                                          nullptr, aggb, C_, B_, nullptr, 0,
                                                          nullptr, nullptr, nullptr, nullptr);
    // gi and gh batched into one dispatch (z=0: gi, z=1: gh)
    gemm_bt<<<dim3(3072 / 128, B_ / 128, 2), 256, 0, stream>>>(aggb, C_, gWihb, C_, gbihf,
                                                               gi, nullptr, 3072, C_, nullptr, 0,
                                                               hb16, gWhhb, gbhhf, gh);
    gru_ew<<<(B_ * C_) / 256, 256, 0, stream>>>(gi, gh, hbuf, hb16);
  }
  gemm_bt<<<dim3(C_ / 128, B_ / 128), 256, 0, stream>>>(hb16, C_, projWb, C_, projbf,
                                                        (float*)d_out, (bf16*)d_out, C_, C_,
                                                        dflag, 1,
                                                        nullptr, nullptr, nullptr, nullptr);
}

// Round 9
// 1967.386 us; speedup vs baseline: 2.4650x; 1.1313x over previous
//
#include <hip/hip_runtime.h>
#include <hip/hip_bf16.h>
#include <stdint.h>

typedef __hip_bfloat16 bf16;
typedef __attribute__((ext_vector_type(8))) short frag16;
typedef __attribute__((ext_vector_type(4))) float f32x4;

#define B_ 2048
#define T_ 64
#define E_ 300
#define H_ 300
#define C_ 1024
#define V_ 50000
#define NE_ 65536
#define HP 320     // padded E/H half of concat-K
#define KC 640     // padded concat K (320 x + 320 h)
#define NP 1280    // padded 4H, gate-interleaved n = 4*j + q

static __device__ __forceinline__ float sigf(float x) {
  x = fminf(fmaxf(x, -30.f), 30.f);
  return 1.f / (1.f + __expf(-x));
}
static __device__ __forceinline__ float tanhfast(float x) {
  x = fminf(fmaxf(x, -15.f), 15.f);
  float e = __expf(2.f * x);
  return (e - 1.f) / (e + 1.f);
}
static __device__ __forceinline__ float ldraw(const void* p, size_t i, int isb) {
  return isb ? __bfloat162float(((const bf16*)p)[i]) : ((const float*)p)[i];
}
static __device__ __forceinline__ short b2s(bf16 b) {
  short s; __builtin_memcpy(&s, &b, 2); return s;
}
static __device__ __forceinline__ short4 f4tob4(float4 v) {
  return make_short4(b2s(__float2bfloat16(v.x)), b2s(__float2bfloat16(v.y)),
                     b2s(__float2bfloat16(v.z)), b2s(__float2bfloat16(v.w)));
}

// Direct global->LDS 16B per lane. LDS dest wave-uniform; lane i lands at
// base + i*16B. Global source per-lane.
static __device__ __forceinline__ void g2l16(const void* g, void* l) {
  __builtin_amdgcn_global_load_lds(
      (const __attribute__((address_space(1))) void*)(uintptr_t)g,
      (__attribute__((address_space(3))) void*)(uintptr_t)l, 16, 0, 0);
}

// Input dtype detector: bit14 of low half-word is 0 in bf16 world (|v|<2),
// ~Bernoulli(0.5) in f32 world (mantissa bits).
__global__ void detect_dtype(const unsigned short* __restrict__ e2, int* __restrict__ flag) {
  __shared__ int red[4];
  int tid = threadIdx.x;
  int ones = 0;
#pragma unroll
  for (int s = 0; s < 16; ++s) ones += (e2[2 * (tid * 16 + s)] >> 14) & 1;
  for (int off = 32; off > 0; off >>= 1) ones += __shfl_down(ones, off, 64);
  if ((tid & 63) == 0) red[tid >> 6] = ones;
  __syncthreads();
  if (tid == 0) {
    int tot = red[0] + red[1] + red[2] + red[3];
    *flag = (tot < 1024) ? 1 : 0;  // 1 = bf16 inputs, 0 = f32 inputs
  }
}

// C[m][n] = sum_k A[m][k]*W[n][k] (+bias[n]); M,N mult of 128, K of 32.
// A,W bf16, bias f32. 3-deep global_load_lds pipeline with counted vmcnt
// ladder 8/4/0 (L=4 loads/wave/tile, 2 tiles in flight in steady state).
// XCD-aware block remap: same-n (W-panel) blocks cluster per XCD
// (requires gridDim.x % 8 == 0 — true for all call sites).
// gridDim.z==2: z==1 uses (A2,W2,bias2,Cf2). outmode=1: d_out raw dtype.
__global__ __launch_bounds__(256) void gemm_bt(
    const bf16* A, int lda, const bf16* W, int ldw, const float* bias,
    float* Cf, bf16* Cb, int ldc, int K,
    const int* __restrict__ rawp, int outmode,
    const bf16* A2, const bf16* W2, const float* bias2, float* Cf2) {
  if (blockIdx.z) { A = A2; W = W2; bias = bias2; Cf = Cf2; Cb = nullptr; }
  __shared__ __align__(16) short As[3][128 * 32];
  __shared__ __align__(16) short Bs[3][128 * 32];
  const int isb = rawp ? *rawp : 1;  // output dtype only
  // XCD remap: id -> (bx, by) with same-bx runs on one XCD (id%8 = XCD).
  const int nxb = gridDim.x;
  const int id = blockIdx.x + nxb * blockIdx.y;
  const int npx = nxb >> 3;
  const int jj = id >> 3;
  const int bx = (id & 7) * npx + (npx > 1 ? jj % npx : 0);
  const int by = npx > 1 ? jj / npx : jj;
  const int n0 = bx * 128, m0 = by * 128;
  const int lane = threadIdx.x & 63, wv = threadIdx.x >> 6;
  const int wm = (wv & 1) * 64, wn = (wv >> 1) * 64;
  // gload geometry: wave wv covers 32 rows (2 calls x 16); lane -> (row,chunk)
  const int gr = lane >> 2;          // row within 16-row call group
  const int gc = (lane & 3) * 8;     // short col within 32-k tile
  const short* pA0 = (const short*)A + (size_t)(m0 + wv * 32 + gr) * lda + gc;
  const short* pA1 = pA0 + (size_t)16 * lda;
  const short* pB0 = (const short*)W + (size_t)(n0 + wv * 32 + gr) * ldw + gc;
  const short* pB1 = pB0 + (size_t)16 * ldw;

  auto issueT = [&](int k0, int buf) {  // 4 VMEM ops per wave
    short* a = &As[buf][wv * 1024];
    short* b = &Bs[buf][wv * 1024];
    g2l16(pA0 + k0, a);
    g2l16(pA1 + k0, a + 512);
    g2l16(pB0 + k0, b);
    g2l16(pB1 + k0, b + 512);
  };

  f32x4 acc[4][4];
#pragma unroll
  for (int i = 0; i < 4; ++i)
#pragma unroll
    for (int j = 0; j < 4; ++j) acc[i][j] = (f32x4){0.f, 0.f, 0.f, 0.f};

  const int nk = K / 32;
  const int krd = (lane >> 4) * 8;
  const int rsel = lane & 15;
  issueT(0, 0);
  if (nk > 1) issueT(32, 1);
  if (nk > 2) issueT(64, 2);
  for (int kk = 0; kk < nk; ++kk) {
    const int cur = kk % 3;
    if (kk + 2 < nk)      asm volatile("s_waitcnt vmcnt(8)" ::: "memory");
    else if (kk + 1 < nk) asm volatile("s_waitcnt vmcnt(4)" ::: "memory");
    else                  asm volatile("s_waitcnt vmcnt(0)" ::: "memory");
    __builtin_amdgcn_s_barrier();
    frag16 af[4], bfg[4];
#pragma unroll
    for (int i = 0; i < 4; ++i) af[i] = *(const frag16*)&As[cur][(wm + i * 16 + rsel) * 32 + krd];
#pragma unroll
    for (int i = 0; i < 4; ++i) bfg[i] = *(const frag16*)&Bs[cur][(wn + i * 16 + rsel) * 32 + krd];
#pragma unroll
    for (int i = 0; i < 4; ++i)
#pragma unroll
      for (int j = 0; j < 4; ++j)
        acc[i][j] = __builtin_amdgcn_mfma_f32_16x16x32_bf16(af[i], bfg[j], acc[i][j], 0, 0, 0);
    asm volatile("" ::: "memory");
    __builtin_amdgcn_s_barrier();  // all waves done reading buf cur
    if (kk + 3 < nk) issueT(32 * (kk + 3), cur);
  }
  const int rq = (lane >> 4) * 4, cq = lane & 15;
#pragma unroll
  for (int j = 0; j < 4; ++j) {
    int cidx = n0 + wn + j * 16 + cq;
    float bv = bias ? bias[cidx] : 0.f;
#pragma unroll
    for (int i = 0; i < 4; ++i) {
      int rbase = m0 + wm + i * 16 + rq;
#pragma unroll
      for (int r = 0; r < 4; ++r) {
        float v = acc[i][j][r] + bv;
        size_t idx = (size_t)(rbase + r) * ldc + cidx;
        if (outmode) {
          if (isb) Cb[idx] = __float2bfloat16(v);
          else Cf[idx] = v;
        } else {
          if (Cf) Cf[idx] = v;
          if (Cb) Cb[idx] = __float2bfloat16(v);
        }
      }
    }
  }
}

// Two-pair norm-accumulate: Spf[b] += concat(hfA,hbA)/||.|| + concat(hfB,hbB)/||.||
// One wave per b (both pairs in one wave -> no RMW race on Spf[b]).
static __device__ __forceinline__ void normacc_row2(
    const bf16* hfA, const bf16* hbA, const bf16* hfB, const bf16* hbB,
    float* __restrict__ Spf, int b, int lane) {
  float vA[10], vB[10];
  float sA = 0.f, sB = 0.f;
#pragma unroll
  for (int s = 0; s < 10; ++s) {
    int d = lane + 64 * s;
    float a = 0.f, c = 0.f;
    if (d < 300) {
      a = __bfloat162float(hfA[d]);
      c = __bfloat162float(hfB[d]);
    } else if (d < 600) {
      a = __bfloat162float(hbA[d - 300]);
      c = __bfloat162float(hbB[d - 300]);
    }
    vA[s] = a; vB[s] = c;
    sA += a * a; sB += c * c;
  }
#pragma unroll
  for (int off = 32; off > 0; off >>= 1) {
    sA += __shfl_xor(sA, off, 64);
    sB += __shfl_xor(sB, off, 64);
  }
  float kA = 1.f / fmaxf(sqrtf(sA), 1e-8f);
  float kB = 1.f / fmaxf(sqrtf(sB), 1e-8f);
  float* dst = Spf + (size_t)b * KC;
#pragma unroll
  for (int s = 0; s < 10; ++s) {
    int d = lane + 64 * s;
    if (d < 600) dst[d] += vA[s] * kA + vB[s] * kB;
  }
}

// Fused bidirectional LSTM timestep. z=0: fwd GEMM (tt=s). z=1: bwd GEMM
// (tt=63-s). z=2: paired normacc (s>=33). fwd stores hf[t<32] in Hfst,
// bwd hb[t>=32] in Hbst. GEMM tile 128(N)x64(M). isb path: 3-deep
// global_load_lds pipeline with counted vmcnt 6/3/0 (L=3 loads/wave/tile).
// XCD-aware remap: each XCD owns 4 m-tiles x all 10 n-tiles (A-panel/emb
// rows become XCD-local L2 hits). f32-emb path: single-buffer fallback.
__global__ __launch_bounds__(256) void lstm_step(
    const void* __restrict__ emb, const bf16* __restrict__ embtail,
    const int* __restrict__ x,
    const bf16* __restrict__ Wcat, const float* __restrict__ bcat,
    bf16* __restrict__ hpad, float* __restrict__ cstate,
    bf16* __restrict__ Hfst, bf16* __restrict__ Hbst, float* __restrict__ Spf,
    int s, const int* __restrict__ flagp) {
  const int pb = s & 1;
  const int lane = threadIdx.x & 63, wv = threadIdx.x >> 6;

  if (blockIdx.z == 2) {  // paired normacc plane (320 blocks)
    if (s >= 33) {
      int bid = blockIdx.x + gridDim.x * blockIdx.y;  // 0..319
      const bf16* hinf = hpad + (size_t)pb * B_ * HP;        // hf[s-1]
      const bf16* hinb = hpad + (size_t)(2 + pb) * B_ * HP;  // hb[64-s]
      const int t1 = s - 1, t2 = 64 - s;
#pragma unroll
      for (int rep = 0; rep < 2; ++rep) {
        int b = bid * 4 + wv + 1280 * rep;
        if (b < B_)
          normacc_row2(hinf + (size_t)b * HP,
                       Hbst + ((size_t)(t1 - 32) * B_ + b) * H_,
                       Hfst + ((size_t)t2 * B_ + b) * H_,
                       hinb + (size_t)b * HP, Spf, b, lane);
      }
    }
    return;
  }

  // LDS: 3 x (A 4KB @ buf*4096, B 8KB @ 12288 + buf*8192) = 36 KB; epi reuses.
  __shared__ __align__(16) char smem[36864];
  float* epi = (float*)smem;  // reused: 64x64 fp32 = 16 KB

  const int dir = blockIdx.z;
  const int tt = dir ? (T_ - 1 - s) : s;
  const int isb = *flagp;
  const bf16* hin = hpad + (size_t)(dir * 2 + pb) * B_ * HP;
  const bf16* Wd = Wcat + (size_t)dir * NP * KC;
  bf16* hout = hpad + (size_t)(dir * 2 + (1 - pb)) * B_ * HP;
  float* cs = cstate + (size_t)dir * B_ * HP;
  // XCD remap: id 0..319 -> (mt 0..31, nt 0..9); mt = (id&7)*4 + ((id>>3)&3)
  // so each XCD (id%8) owns 4 contiguous m-tiles x all 10 n-tiles.
  const int id = blockIdx.x + gridDim.x * blockIdx.y;
  const int jj = id >> 3;
  const int mt = (id & 7) * 4 + (jj & 3);
  const int nt = jj >> 2;
  const int n0 = nt * 128, m0 = mt * 64;
  const int wm = (wv & 1) * 32, wn = (wv >> 1) * 64;
  // gload geometry
  const int gr = lane >> 2;        // row within 16-row call group
  const int gc = (lane & 3) * 8;   // short col within 32-k tile
  const int arow = m0 + wv * 16 + gr;            // A row owned by this lane
  const int tok = x[arow * T_ + tt];             // emb token for this row
  const short* es = (const short*)emb;
  const float* ef = (const float*)emb;
  const short* px = es + (size_t)tok * E_ + gc;              // bf16 emb row
  const short* ptail = (const short*)embtail + (size_t)tok * 32 + gc;
  const short* ph = (const short*)hin + (size_t)arow * HP + gc;
  const short* pB0 = (const short*)Wd + (size_t)(n0 + wv * 32 + gr) * KC + gc;
  const short* pB1 = pB0 + (size_t)16 * KC;

  auto issueT = [&](int k0, int buf) {  // 3 VMEM ops per wave
    short* a = (short*)(smem + buf * 4096) + wv * 512;
    short* b = (short*)(smem + 12288 + buf * 8192) + wv * 1024;
    if (k0 < HP) {
      // chunks never straddle E_ for k0<288 (max end 256+24+8=288);
      // k0==288 reads the prepadded tail table (cols 288..319).
      g2l16(k0 == 288 ? ptail : (px + k0), a);
    } else {
      g2l16(ph + (k0 - HP), a);  // hpad cols 300..319 are persistent zeros
    }
    g2l16(pB0 + k0, b);
    g2l16(pB1 + k0, b + 512);
  };

  f32x4 acc[2][4];
#pragma unroll
  for (int i = 0; i < 2; ++i)
#pragma unroll
    for (int j = 0; j < 4; ++j) acc[i][j] = (f32x4){0.f, 0.f, 0.f, 0.f};

  const int rsel = lane & 15, krd = (lane >> 4) * 8;
  const int NKT = KC / 32;  // 20

  auto mfma8 = [&](const short* Ap, const short* Bp) {
    frag16 af[2], bfg[4];
#pragma unroll
    for (int i = 0; i < 2; ++i) af[i] = *(const frag16*)&Ap[(wm + i * 16 + rsel) * 32 + krd];
#pragma unroll
    for (int j = 0; j < 4; ++j) bfg[j] = *(const frag16*)&Bp[(wn + j * 16 + rsel) * 32 + krd];
#pragma unroll
    for (int i = 0; i < 2; ++i)
#pragma unroll
      for (int j = 0; j < 4; ++j)
        acc[i][j] = __builtin_amdgcn_mfma_f32_16x16x32_bf16(af[i], bfg[j], acc[i][j], 0, 0, 0);
  };

  if (isb) {
    // 3-deep counted-vmcnt pipeline
    issueT(0, 0);
    issueT(32, 1);
    issueT(64, 2);
    for (int kk = 0; kk < NKT; ++kk) {
      const int cur = kk % 3;
      if (kk + 2 < NKT)      asm volatile("s_waitcnt vmcnt(6)" ::: "memory");
      else if (kk + 1 < NKT) asm volatile("s_waitcnt vmcnt(3)" ::: "memory");
      else                   asm volatile("s_waitcnt vmcnt(0)" ::: "memory");
      __builtin_amdgcn_s_barrier();
      mfma8((const short*)(smem + cur * 4096), (const short*)(smem + 12288 + cur * 8192));
      asm volatile("" ::: "memory");
      __builtin_amdgcn_s_barrier();  // all waves done reading buf cur
      if (kk + 3 < NKT) issueT(32 * (kk + 3), cur);
    }
  } else {
    // f32-emb fallback: single buffer, reg-staged x-half, full barriers
    short* As0 = (short*)smem;
    short* Bs0 = (short*)(smem + 12288);
    for (int kk = 0; kk < NKT; ++kk) {
      const int k0 = kk * 32;
      if (k0 < HP) {
        int c0 = k0 + gc;
        float4 fa = (c0 < E_) ? *(const float4*)(ef + (size_t)tok * E_ + c0)
                              : make_float4(0.f, 0.f, 0.f, 0.f);
        float4 fb = (c0 + 4 < E_) ? *(const float4*)(ef + (size_t)tok * E_ + c0 + 4)
                                  : make_float4(0.f, 0.f, 0.f, 0.f);
        short* d = As0 + (wv * 16 + gr) * 32 + gc;
        *(short4*)d = f4tob4(fa);
        *(short4*)(d + 4) = f4tob4(fb);
      } else {
        g2l16(ph + (k0 - HP), As0 + wv * 512);
      }
      g2l16(pB0 + k0, Bs0 + wv * 1024);
      g2l16(pB1 + k0, Bs0 + wv * 1024 + 512);
      __syncthreads();
      mfma8(As0, Bs0);
      __syncthreads();
    }
  }

  const int rq = (lane >> 4) * 4, cq = lane & 15;
#pragma unroll
  for (int p = 0; p < 2; ++p) {
    if (wn == p * 64) {
#pragma unroll
      for (int j = 0; j < 4; ++j) {
        int cl = j * 16 + cq;
        float bv = bcat[dir * NP + n0 + p * 64 + cl];
#pragma unroll
        for (int i = 0; i < 2; ++i) {
          int rl = wm + i * 16 + rq;
#pragma unroll
          for (int r = 0; r < 4; ++r) epi[(rl + r) * 64 + cl] = acc[i][j][r] + bv;
        }
      }
    }
    __syncthreads();
    int jbase = (n0 + p * 64) >> 2;
    for (int it = threadIdx.x; it < 64 * 16; it += 256) {
      int rl = it >> 4, jl = it & 15;
      int jg = jbase + jl;
      if (jg < H_) {
        const float* row = epi + rl * 64 + jl * 4;
        float iv = sigf(row[0]);
        float fv = sigf(row[1]);
        float gv = tanhfast(row[2]);
        float ov = sigf(row[3]);
        int b = m0 + rl;
        float c = fv * cs[(size_t)b * HP + jg] + iv * gv;
        float h = ov * tanhfast(c);
        cs[(size_t)b * HP + jg] = c;
        bf16 hb = __float2bfloat16(h);
        hout[(size_t)b * HP + jg] = hb;
        if (dir) {
          if (tt >= 32) Hbst[((size_t)(tt - 32) * B_ + b) * H_ + jg] = hb;
        } else if (tt < 32) {
          Hfst[((size_t)tt * B_ + b) * H_ + jg] = hb;
        }
      }
    }
    __syncthreads();
  }
}

// Cleanup pairs t=63 (hf: fwd hout plane 0, hb: Hbst[31]) and t=0
// (hf: Hfst[0], hb: bwd hout plane 2) after the fused loop.
__global__ __launch_bounds__(256) void normacc_fin(const bf16* __restrict__ hpad,
                                                   const bf16* __restrict__ Hfst,
                                                   const bf16* __restrict__ Hbst,
                                                   float* __restrict__ Spf) {
  int b = blockIdx.x * 4 + (threadIdx.x >> 6);
  int lane = threadIdx.x & 63;
  normacc_row2(hpad + (size_t)b * HP,
               Hbst + ((size_t)31 * B_ + b) * H_,
               Hfst + (size_t)b * H_,
               hpad + (size_t)2 * B_ * HP + (size_t)b * HP, Spf, b, lane);
}

// Merged prep: blocks [0,1024) = labelnorm; blocks >=1024 = elementwise
// {prep_wcat | transpose_ggc | embtail} by index range.
__global__ void prep_all(const void* __restrict__ Wih_f, const void* __restrict__ Whh_f,
                         const void* __restrict__ bih_f, const void* __restrict__ bhh_f,
                         const void* __restrict__ Wih_b, const void* __restrict__ Whh_b,
                         const void* __restrict__ bih_b, const void* __restrict__ bhh_b,
                         const void* __restrict__ label, const void* __restrict__ ggcw,
                         const void* __restrict__ emb,
                         bf16* __restrict__ Wcat, float* __restrict__ bcat,
                         bf16* __restrict__ lnp, bf16* __restrict__ ggct,
                         bf16* __restrict__ embtail,
                         const int* __restrict__ flagp) {
  const int isb = *flagp;
  if (blockIdx.x < 1024) {  // labelnorm, l = blockIdx.x
    int l = blockIdx.x, tid = threadIdx.x;
    __shared__ float red[4];
    float v[3];
    float ss = 0.f;
#pragma unroll
    for (int s = 0; s < 3; ++s) {
      int d = tid + 256 * s;
      v[s] = (d < 600) ? ldraw(label, (size_t)l * 600 + d, isb) : 0.f;
      ss += v[s] * v[s];
    }
    for (int off = 32; off > 0; off >>= 1) ss += __shfl_down(ss, off, 64);
    if ((tid & 63) == 0) red[tid >> 6] = ss;
    __syncthreads();
    float scale = 1.f / fmaxf(sqrtf(red[0] + red[1] + red[2] + red[3]), 1e-8f);
#pragma unroll
    for (int s = 0; s < 3; ++s) {
      int d = tid + 256 * s;
      if (d < KC) lnp[(size_t)l * KC + d] = __float2bfloat16(v[s] * scale);
    }
    return;
  }
  int i = (blockIdx.x - 1024) * 256 + threadIdx.x;
  if (i < 2 * NP * KC) {  // prep_wcat
    int k = i % KC;
    int n = (i / KC) % NP;
    int dir = i / (KC * NP);
    int j = n >> 2, q = n & 3;
    const void* Wih = dir ? Wih_b : Wih_f;
    const void* Whh = dir ? Whh_b : Whh_f;
    float v = 0.f;
    if (j < H_) {
      int row = q * H_ + j;
      if (k < E_) v = ldraw(Wih, (size_t)row * E_ + k, isb);
      else if (k >= HP && k < HP + H_) v = ldraw(Whh, (size_t)row * H_ + (k - HP), isb);
    }
    Wcat[i] = __float2bfloat16(v);
    if (k == 0) {
      const void* bih = dir ? bih_b : bih_f;
      const void* bhh = dir ? bhh_b : bhh_f;
      bcat[dir * NP + n] =
          (j < H_) ? (ldraw(bih, q * H_ + j, isb) + ldraw(bhh, q * H_ + j, isb)) : 0.f;
    }
    return;
  }
  i -= 2 * NP * KC;
  if (i < 2 * C_ * C_) {  // transpose_ggc: Wt[l][n][k] = ggc[l][k][n]
    int k = i & 1023, n = (i >> 10) & 1023, l = i >> 20;
    size_t src = ((size_t)l << 20) | ((size_t)k << 10) | (size_t)n;
    ggct[i] = __float2bfloat16(ldraw(ggcw, src, isb));
    return;
  }
  i -= 2 * C_ * C_;
  if (i < V_ * 32) {  // embtail[v][c] = (c<12) ? emb[v][288+c] : 0
    int v = i >> 5, c = i & 31;
    float val = (c < E_ - 288) ? ldraw(emb, (size_t)v * E_ + 288 + c, isb) : 0.f;
    embtail[i] = __float2bfloat16(val);
  }
}

// Merged phase-2 prep: raw GRU/proj weights -> bf16, biases -> f32.
// Runs AFTER phase 1 (outputs alias the dead Hbst region).
__global__ void prep2(const void* __restrict__ gWih, const void* __restrict__ gWhh,
                      const void* __restrict__ projW, const void* __restrict__ gbih,
                      const void* __restrict__ gbhh, const void* __restrict__ projb,
                      bf16* __restrict__ gWihb, bf16* __restrict__ gWhhb,
                      bf16* __restrict__ projWb, float* __restrict__ gbihf,
                      float* __restrict__ gbhhf, float* __restrict__ projbf,
                      const int* __restrict__ flagp) {
  const int isb = *flagp;
  int i = blockIdx.x * 256 + threadIdx.x;
  if (i < 3072 * C_) { gWihb[i] = __float2bfloat16(ldraw(gWih, i, isb)); return; }
  i -= 3072 * C_;
  if (i < 3072 * C_) { gWhhb[i] = __float2bfloat16(ldraw(gWhh, i, isb)); return; }
  i -= 3072 * C_;
  if (i < C_ * C_) { projWb[i] = __float2bfloat16(ldraw(projW, i, isb)); return; }
  i -= C_ * C_;
  if (i < 3072) { gbihf[i] = ldraw(gbih, i, isb); return; }
  i -= 3072;
  if (i < 3072) { gbhhf[i] = ldraw(gbhh, i, isb); return; }
  i -= 3072;
  if (i < C_) { projbf[i] = ldraw(projb, i, isb); }
}

__global__ void zero_u4(uint4* __restrict__ p, int n16) {
  int i = blockIdx.x * 256 + threadIdx.x;
  if (i < n16) p[i] = make_uint4(0u, 0u, 0u, 0u);
}

// Dense adjacency counts: cnt[d][s] = #edges s->d (int atomics, 65536 total).
__global__ void edge_cnt(const int* __restrict__ ei, int* __restrict__ cnt) {
  int e = blockIdx.x * 256 + threadIdx.x;
  if (e < NE_) {
    int s = ei[e], d = ei[NE_ + e];
    atomicAdd(&cnt[(size_t)d * B_ + s], 1);
  }
}
__global__ void cnt2bf(const int* __restrict__ cnt, bf16* __restrict__ A) {
  int i = blockIdx.x * 256 + threadIdx.x;  // 4M
  A[i] = __float2bfloat16((float)cnt[i]);
}

__global__ void gru_ew(const float* __restrict__ gi, const float* __restrict__ gh,
                       float* __restrict__ h, bf16* __restrict__ hb16) {
  int i = blockIdx.x * 256 + threadIdx.x;
  int b = i >> 10, j = i & 1023;
  const float* gib = gi + (size_t)b * 3072;
  const float* ghb = gh + (size_t)b * 3072;
  float r = sigf(gib[j] + ghb[j]);
  float z = sigf(gib[1024 + j] + ghb[1024 + j]);
  float n = tanhfast(gib[2048 + j] + r * ghb[2048 + j]);
  float hv = (1.f - z) * n + z * h[i];
  h[i] = hv;
  hb16[i] = __float2bfloat16(hv);
}

__global__ void spcvt(const float* __restrict__ Spf, bf16* __restrict__ Sp) {
  int i = blockIdx.x * 256 + threadIdx.x;
  Sp[i] = __float2bfloat16(Spf[i]);
}

__global__ void sentinel(bf16* __restrict__ o, int n, float v) {
  int i = blockIdx.x * 256 + threadIdx.x;
  if (i < n) o[i] = __float2bfloat16(v);
}

extern "C" void kernel_launch(void* const* d_in, const int* in_sizes, int n_in,
                              void* d_out, int out_size, void* d_ws, size_t ws_size,
                              hipStream_t stream) {
  const int* x = (const int*)d_in[0];
  const int* ei = (const int*)d_in[1];
  const void* emb = d_in[2];
  const void* Wih_f = d_in[3];
  const void* Whh_f = d_in[4];
  const void* bih_f = d_in[5];
  const void* bhh_f = d_in[6];
  const void* Wih_b = d_in[7];
  const void* Whh_b = d_in[8];
  const void* bih_b = d_in[9];
  const void* bhh_b = d_in[10];
  const void* label = d_in[11];
  const void* ggcw = d_in[12];
  const void* gWih = d_in[13];
  const void* gWhh = d_in[14];
  const void* gbih = d_in[15];
  const void* gbhh = d_in[16];
  const void* projW = d_in[17];
  const void* projb = d_in[18];
  (void)in_sizes; (void)n_in;

  const size_t NEED = (size_t)112 * 1024 * 1024;
  if (ws_size < NEED) {
    float v = 100.f + (float)(ws_size >> 24);
    sentinel<<<(out_size + 255) / 256, 256, 0, stream>>>((bf16*)d_out, out_size, v);
    return;
  }

  char* w = (char*)d_ws;
  size_t off = 0;
  auto alloc = [&](size_t bytes) {
    char* p = w + off;
    off += (bytes + 255) & ~(size_t)255;
    return p;
  };
  // ---- persistent (~14.6 MB) ----
  int* dflag = (int*)alloc(256);
  bf16* Wcat = (bf16*)alloc((size_t)2 * NP * KC * 2);
  float* bcat = (float*)alloc((size_t)2 * NP * 4);
  bf16* lnp = (bf16*)alloc((size_t)C_ * KC * 2);
  bf16* ggct = (bf16*)alloc((size_t)2 * C_ * C_ * 2);
  bf16* Sp = (bf16*)alloc((size_t)B_ * KC * 2);
  bf16* embtail = (bf16*)alloc((size_t)V_ * 32 * 2);
  const size_t phase_base = off;
  // ---- phase 1 (LSTM): ~94.4 MB (Spf,hpad,cst contiguous for one zero) ----
  float* Spf = (float*)alloc((size_t)B_ * KC * 4);
  bf16* hpad = (bf16*)alloc((size_t)4 * B_ * HP * 2);
  float* cst = (float*)alloc((size_t)2 * B_ * HP * 4);
  bf16* Hfst = (bf16*)alloc((size_t)32 * B_ * H_ * 2);  // hf[t] for t=0..31
  bf16* Hbst = (bf16*)alloc((size_t)32 * B_ * H_ * 2);  // hb[t] for t=32..63
  // ---- phase 2 (graph): ~94.5 MB, aliases phase 1 ----
  off = phase_base;
  float* hbuf = (float*)alloc((size_t)B_ * C_ * 4);
  bf16* hb16 = (bf16*)alloc((size_t)B_ * C_ * 2);
  bf16* m1t = (bf16*)alloc((size_t)C_ * B_ * 2);     // m transposed [c][s]
  bf16* aggb = (bf16*)alloc((size_t)B_ * C_ * 2);
  bf16* Acnt = (bf16*)alloc((size_t)B_ * B_ * 2);    // dense adjacency counts
  float* gi = (float*)alloc((size_t)B_ * 3072 * 4);  // cnt(i32, 16MB) aliases head of gi
  float* gh = (float*)alloc((size_t)B_ * 3072 * 4);
  bf16* gWihb = (bf16*)alloc((size_t)3072 * C_ * 2);  // pre-converted bf16 weights
  bf16* gWhhb = (bf16*)alloc((size_t)3072 * C_ * 2);
  bf16* projWb = (bf16*)alloc((size_t)C_ * C_ * 2);
  float* gbihf = (float*)alloc(3072 * 4);
  float* gbhhf = (float*)alloc(3072 * 4);
  float* projbf = (float*)alloc(C_ * 4);
  int* cnt = (int*)gi;

  // ---- dtype detection + merged prep ----
  detect_dtype<<<1, 256, 0, stream>>>((const unsigned short*)emb, dflag);
  prep_all<<<1024 + (2 * NP * KC + 2 * C_ * C_ + V_ * 32) / 256, 256, 0, stream>>>(
      Wih_f, Whh_f, bih_f, bhh_f, Wih_b, Whh_b, bih_b, bhh_b, label, ggcw, emb,
      Wcat, bcat, lnp, ggct, embtail, dflag);
  // one zero over contiguous Spf+hpad+cst (3 x 5,242,880 B, 256-aligned)
  zero_u4<<<(3 * 327680) / 256, 256, 0, stream>>>((uint4*)Spf, 3 * 327680);

  // ---- phase 1: fused bidir LSTM, 64 sequential dispatches ----
  for (int s = 0; s < T_; ++s)
    lstm_step<<<dim3(NP / 128, B_ / 64, 3), 256, 0, stream>>>(emb, embtail, x, Wcat, bcat,
                                                              hpad, cst, Hfst, Hbst, Spf,
                                                              s, dflag);
  normacc_fin<<<B_ / 4, 256, 0, stream>>>(hpad, Hfst, Hbst, Spf);
  spcvt<<<(B_ * KC) / 256, 256, 0, stream>>>(Spf, Sp);

  // ---- phase 2 prep (after phase 1: outputs alias dead Hbst region) ----
  prep2<<<(2 * 3072 * C_ + C_ * C_ + 2 * 3072 + C_) / 256, 256, 0, stream>>>(
      gWih, gWhh, projW, gbih, gbhh, projb, gWihb, gWhhb, projWb, gbihf, gbhhf, projbf, dflag);

  // ---- phase 2: label scores + GatedGraphConv (dense-adjacency GEMM) + proj ----
  gemm_bt<<<dim3(C_ / 128, B_ / 128), 256, 0, stream>>>(Sp, KC, lnp, KC, nullptr,
                                                        hbuf, hb16, C_, KC, nullptr, 0,
                                                        nullptr, nullptr, nullptr, nullptr);
  // adjacency counts (built once, reused by both layers)
  zero_u4<<<(B_ * B_ * 4 / 16) / 256, 256, 0, stream>>>((uint4*)cnt, B_ * B_ * 4 / 16);
  edge_cnt<<<NE_ / 256, 256, 0, stream>>>(ei, cnt);
  cnt2bf<<<(B_ * B_) / 256, 256, 0, stream>>>(cnt, Acnt);
  for (int l = 0; l < 2; ++l) {
    // m1t[c][s] = sum_k ggcw[l][k][c] * h[s][k]   (A/W roles swapped)
    gemm_bt<<<dim3(B_ / 128, C_ / 128), 256, 0, stream>>>(ggct + (size_t)l * C_ * C_, C_,
                                                          hb16, C_, nullptr,
                                                          nullptr, m1t, B_, C_, nullptr, 0,
                                                          nullptr, nullptr, nullptr, nullptr);
    // agg[d][c] = sum_s Acnt[d][s] * m1t[c][s]
    gemm_bt<<<dim3(C_ / 128, B_ / 128), 256, 0, stream>>>(Acnt, B_, m1t, B_, nullptr,
                                                          nullptr, aggb, C_, B_, nullptr, 0,
                                                          nullptr, nullptr, nullptr, nullptr);
    // gi and gh batched into one dispatch (z=0: gi, z=1: gh)
    gemm_bt<<<dim3(3072 / 128, B_ / 128, 2), 256, 0, stream>>>(aggb, C_, gWihb, C_, gbihf,
                                                               gi, nullptr, 3072, C_, nullptr, 0,
                                                               hb16, gWhhb, gbhhf, gh);
    gru_ew<<<(B_ * C_) / 256, 256, 0, stream>>>(gi, gh, hbuf, hb16);
  }
  gemm_bt<<<dim3(C_ / 128, B_ / 128), 256, 0, stream>>>(hb16, C_, projWb, C_, projbf,
                                                        (float*)d_out, (bf16*)d_out, C_, C_,
                                                        dflag, 1,
                                                        nullptr, nullptr, nullptr, nullptr);
}